// Round 14
// baseline (221.849 us; speedup 1.0000x reference)
//
#include <hip/hip_runtime.h>
#include <hip/hip_bf16.h>
#include <math.h>

// ---------------------------------------------------------------------------
// TransformerLayer: B=2 S=2048 D=1024 H=16 HD=64. I/O f32, internals bf16.
// Round 14: attention (1) software-pipelined K-tile: QK(sub0);QK(sub1);
// SM/PV(sub0);SM/PV(sub1) so subtile-1's QK MFMAs overlap subtile-0's softmax
// VALU (within-wave pipe overlap); (2) XCD-chunk block swizzle (4 whole heads
// per XCD -> K/V L2-resident). GEMMs/LN/addpe unchanged from r13.
// ---------------------------------------------------------------------------

#define B_ 2
#define S_ 2048
#define D_ 1024
#define H_ 16
#define HD_ 64

typedef __bf16 bf16_t;
typedef __bf16 bf16x8 __attribute__((ext_vector_type(8)));
typedef __bf16 bf16x4v __attribute__((ext_vector_type(4)));
typedef float f32x4 __attribute__((ext_vector_type(4)));
typedef float f32x16 __attribute__((ext_vector_type(16)));
typedef unsigned int u32;

__device__ __forceinline__ f32x4 mfma16(bf16x8 a, bf16x8 b, f32x4 c) {
  return __builtin_amdgcn_mfma_f32_16x16x32_bf16(a, b, c, 0, 0, 0);
}
__device__ __forceinline__ f32x16 mfma32(bf16x8 a, bf16x8 b, f32x16 c) {
  return __builtin_amdgcn_mfma_f32_32x32x16_bf16(a, b, c, 0, 0, 0);
}
__device__ __forceinline__ u32 pkbf(float a, float b) {
  union { bf16_t h[2]; u32 u; } t;
  t.h[0] = (bf16_t)a; t.h[1] = (bf16_t)b;
  return t.u;
}
__device__ __forceinline__ float fexp2(float x) {       // single v_exp_f32
  return __builtin_amdgcn_exp2f(x);
}

// global -> LDS direct copy, 16B/lane. LDS dest: wave-uniform base + lane*16.
__device__ __forceinline__ void gload_lds16(const bf16_t* g, bf16_t* l) {
  __builtin_amdgcn_global_load_lds((const __attribute__((address_space(1))) void*)g,
                                   (__attribute__((address_space(3))) void*)l,
                                   16, 0, 0);
}

// ---------------------------------------------------------------------------
// Kernel 0: convert 6 f32 weight matrices (D x D) to bf16, contiguous in dst.
// ---------------------------------------------------------------------------
__global__ __launch_bounds__(256) void cvtw_kernel(
    const float* __restrict__ w0, const float* __restrict__ w1,
    const float* __restrict__ w2, const float* __restrict__ w3,
    const float* __restrict__ w4, const float* __restrict__ w5,
    bf16_t* __restrict__ dst) {
  const int wsel = blockIdx.y;
  const float* src = wsel == 0 ? w0 : wsel == 1 ? w1 : wsel == 2 ? w2
                   : wsel == 3 ? w3 : wsel == 4 ? w4 : w5;
  const size_t off = (size_t)blockIdx.x * 1024 + threadIdx.x * 4;
  float4 v = *(const float4*)(src + off);
  bf16x4v r;
  r[0] = (bf16_t)v.x; r[1] = (bf16_t)v.y; r[2] = (bf16_t)v.z; r[3] = (bf16_t)v.w;
  *(bf16x4v*)(dst + (size_t)wsel * (D_ * D_) + off) = r;
}

// ---------------------------------------------------------------------------
// Kernel 1: positional encoding + add; f32 in -> bf16 out (q,k,v one pass).
// ---------------------------------------------------------------------------
__global__ __launch_bounds__(256) void addpe_kernel(
    const float* __restrict__ q, const float* __restrict__ k,
    const float* __restrict__ v,
    bf16_t* __restrict__ qo, bf16_t* __restrict__ ko, bf16_t* __restrict__ vo) {
  const int row = blockIdx.x;            // b*S + s
  const int s = row & (S_ - 1);
  const int d0 = threadIdx.x * 4;
  const size_t base = (size_t)row * D_ + d0;
  float pe[4];
#pragma unroll
  for (int p = 0; p < 2; ++p) {
    float div = __expf((float)(d0 + 2 * p) * -0.008994473019508f);
    float rev = (float)s * div * 0.15915494309189535f;   // ang / (2*pi)
    float rf = rev - floorf(rev);
    pe[2 * p]     = __builtin_amdgcn_sinf(rf);
    pe[2 * p + 1] = __builtin_amdgcn_cosf(rf);
  }
  float4 qv = *(const float4*)&q[base];
  float4 kv = *(const float4*)&k[base];
  float4 vv = *(const float4*)&v[base];
  bf16x4v qr, kr, vr;
  qr[0] = (bf16_t)(qv.x + pe[0]); qr[1] = (bf16_t)(qv.y + pe[1]);
  qr[2] = (bf16_t)(qv.z + pe[2]); qr[3] = (bf16_t)(qv.w + pe[3]);
  kr[0] = (bf16_t)(kv.x + pe[0]); kr[1] = (bf16_t)(kv.y + pe[1]);
  kr[2] = (bf16_t)(kv.z + pe[2]); kr[3] = (bf16_t)(kv.w + pe[3]);
  vr[0] = (bf16_t)(vv.x + pe[0]); vr[1] = (bf16_t)(vv.y + pe[1]);
  vr[2] = (bf16_t)(vv.z + pe[2]); vr[3] = (bf16_t)(vv.w + pe[3]);
  *(bf16x4v*)&qo[base] = qr;
  *(bf16x4v*)&ko[base] = kr;
  *(bf16x4v*)&vo[base] = vr;
}

// ---------------------------------------------------------------------------
// Kernel 2a: singles NT GEMM, tile 128x64 (512 blocks, XCD-chunk swizzled),
// BK=32, 4 waves (2x2, each 64x32), 2-phase dbuf, all-gload_lds.
// EPI: 0 plain, 1 +bias, 2 +bias+relu
// ---------------------------------------------------------------------------
template <int EPI>
__global__ __launch_bounds__(256) void gemm_s(
    const bf16_t* __restrict__ A, const bf16_t* __restrict__ Wb,
    const float* __restrict__ bias, bf16_t* __restrict__ C) {
  constexpr int Kd = 1024, NT = Kd / 32;
  __shared__ alignas(16) bf16_t As[2][128 * 32];
  __shared__ alignas(16) bf16_t Bs[2][64 * 32];
  const int t = threadIdx.x, lane = t & 63, wid = t >> 6;
  // XCD-chunk swizzle (m204, nwg%8==0): 512 blocks = 8 XCDs x 64.
  const int bid = blockIdx.y * 16 + blockIdx.x;
  const int virt = (bid & 7) * 64 + (bid >> 3);
  const int m0 = (virt >> 4) * 128, n0 = (virt & 15) * 64;

  const bf16_t* Asrc0 = A + (size_t)(m0 + wid * 16 + (lane >> 2)) * Kd + (lane & 3) * 8;
  const bf16_t* Asrc1 = Asrc0 + (size_t)64 * Kd;
  const bf16_t* Wsrc = Wb + (size_t)(n0 + wid * 16 + (lane >> 2)) * Kd + (lane & 3) * 8;

  const f32x4 zero = {0.f, 0.f, 0.f, 0.f};
  f32x4 acc[4][2];
#pragma unroll
  for (int m = 0; m < 4; ++m) { acc[m][0] = zero; acc[m][1] = zero; }

  gload_lds16(Asrc0, &As[0][wid * 512]);
  gload_lds16(Asrc1, &As[0][2048 + wid * 512]);
  gload_lds16(Wsrc,  &Bs[0][wid * 512]);

  const int wr = wid >> 1, wc = wid & 1;
#pragma unroll 2
  for (int kt = 0; kt < NT; ++kt) {
    __syncthreads();
    const int cur = kt & 1, nxt = cur ^ 1;
    if (kt + 1 < NT) {
      const int k0 = (kt + 1) * 32;
      gload_lds16(Asrc0 + k0, &As[nxt][wid * 512]);
      gload_lds16(Asrc1 + k0, &As[nxt][2048 + wid * 512]);
      gload_lds16(Wsrc + k0,  &Bs[nxt][wid * 512]);
    }
    bf16x8 af[4], bfr[2];
#pragma unroll
    for (int m = 0; m < 4; ++m)
      af[m] = *(const bf16x8*)&As[cur][(wr * 64 + m * 16 + (lane & 15)) * 32 + (lane >> 4) * 8];
#pragma unroll
    for (int n = 0; n < 2; ++n)
      bfr[n] = *(const bf16x8*)&Bs[cur][(wc * 32 + n * 16 + (lane & 15)) * 32 + (lane >> 4) * 8];
    __builtin_amdgcn_s_setprio(1);
#pragma unroll
    for (int m = 0; m < 4; ++m)
#pragma unroll
      for (int n = 0; n < 2; ++n)
        acc[m][n] = mfma16(af[m], bfr[n], acc[m][n]);
    __builtin_amdgcn_s_setprio(0);
  }

  const int rbase = m0 + wr * 64 + (lane >> 4) * 4;
  const int cbase = n0 + wc * 32 + (lane & 15);
#pragma unroll
  for (int n = 0; n < 2; ++n) {
    const int col = cbase + n * 16;
    float bv = (EPI >= 1) ? bias[col] : 0.f;
#pragma unroll
    for (int m = 0; m < 4; ++m)
#pragma unroll
      for (int r = 0; r < 4; ++r) {
        float vv = acc[m][n][r] + bv;
        if (EPI == 2) vv = fmaxf(vv, 0.f);
        C[(size_t)(rbase + m * 16 + r) * D_ + col] = (bf16_t)vv;
      }
  }
}

// ---------------------------------------------------------------------------
// Kernel 2b: QKV batched GEMM, tile 128x128 (768 blocks, XCD-chunk swizzled),
// BK=32, 4 waves (2x2, each 64x64), 2-phase dbuf. r9-proven body.
// virt z: 0=Q, 1=K, 2=V^T out (scattered store).
// ---------------------------------------------------------------------------
__global__ __launch_bounds__(256) void gemm_qkv(
    const bf16_t* __restrict__ a0p, const bf16_t* __restrict__ a1p,
    const bf16_t* __restrict__ a2p,
    const bf16_t* __restrict__ w0p, const bf16_t* __restrict__ w1p,
    const bf16_t* __restrict__ w2p,
    bf16_t* __restrict__ o0, bf16_t* __restrict__ o1, bf16_t* __restrict__ o2) {
  constexpr int Kd = 1024, NT = Kd / 32;
  __shared__ alignas(16) bf16_t As[2][128 * 32];
  __shared__ alignas(16) bf16_t Bs[2][128 * 32];
  const int t = threadIdx.x, lane = t & 63, wid = t >> 6;
  const int g = lane >> 4, c16 = lane & 15;
  // XCD-chunk swizzle (m204, nwg%8==0): 768 blocks = 8 XCDs x 96.
  const int bid = blockIdx.z * 256 + blockIdx.y * 8 + blockIdx.x;
  const int virt = (bid & 7) * 96 + (bid >> 3);
  const int zz = virt >> 8;
  const int m0 = ((virt >> 3) & 31) * 128, n0 = (virt & 7) * 128;

  const bf16_t* A = a0p;
  const bf16_t* Wb = w0p;
  if (zz == 1) { A = a1p; Wb = w1p; }
  else if (zz == 2) { A = a2p; Wb = w2p; }

  const bf16_t* Asrc0 = A + (size_t)(m0 + wid * 16 + (lane >> 2)) * Kd + (lane & 3) * 8;
  const bf16_t* Asrc1 = Asrc0 + (size_t)64 * Kd;
  const bf16_t* Wsrc0 = Wb + (size_t)(n0 + wid * 16 + (lane >> 2)) * Kd + (lane & 3) * 8;
  const bf16_t* Wsrc1 = Wsrc0 + (size_t)64 * Kd;

  const f32x4 zero = {0.f, 0.f, 0.f, 0.f};
  f32x4 acc[4][4];
#pragma unroll
  for (int m = 0; m < 4; ++m)
#pragma unroll
    for (int n = 0; n < 4; ++n) acc[m][n] = zero;

  gload_lds16(Asrc0, &As[0][wid * 512]);
  gload_lds16(Asrc1, &As[0][2048 + wid * 512]);
  gload_lds16(Wsrc0, &Bs[0][wid * 512]);
  gload_lds16(Wsrc1, &Bs[0][2048 + wid * 512]);

  const int wr = wid >> 1, wc = wid & 1;
#pragma unroll 2
  for (int kt = 0; kt < NT; ++kt) {
    __syncthreads();
    const int cur = kt & 1, nxt = cur ^ 1;
    if (kt + 1 < NT) {
      const int k0 = (kt + 1) * 32;
      gload_lds16(Asrc0 + k0, &As[nxt][wid * 512]);
      gload_lds16(Asrc1 + k0, &As[nxt][2048 + wid * 512]);
      gload_lds16(Wsrc0 + k0, &Bs[nxt][wid * 512]);
      gload_lds16(Wsrc1 + k0, &Bs[nxt][2048 + wid * 512]);
    }
    bf16x8 af[4], bfr[4];
#pragma unroll
    for (int m = 0; m < 4; ++m)
      af[m] = *(const bf16x8*)&As[cur][(wr * 64 + m * 16 + c16) * 32 + g * 8];
#pragma unroll
    for (int n = 0; n < 4; ++n)
      bfr[n] = *(const bf16x8*)&Bs[cur][(wc * 64 + n * 16 + c16) * 32 + g * 8];
    __builtin_amdgcn_s_setprio(1);
#pragma unroll
    for (int m = 0; m < 4; ++m)
#pragma unroll
      for (int n = 0; n < 4; ++n)
        acc[m][n] = mfma16(af[m], bfr[n], acc[m][n]);
    __builtin_amdgcn_s_setprio(0);
  }

  const int rbase = m0 + wr * 64 + g * 4;
  const int cbase = n0 + wc * 64 + c16;
  if (zz == 2) {
#pragma unroll
    for (int n = 0; n < 4; ++n) {
      const int col = cbase + n * 16;
#pragma unroll
      for (int m = 0; m < 4; ++m)
#pragma unroll
        for (int r = 0; r < 4; ++r) {
          const int row = rbase + m * 16 + r;
          const int bb = row >> 11, ss = row & (S_ - 1);
          o2[(size_t)bb * D_ * S_ + (size_t)col * S_ + ss] = (bf16_t)acc[m][n][r];
        }
    }
  } else {
    bf16_t* C = (zz == 1) ? o1 : o0;
#pragma unroll
    for (int n = 0; n < 4; ++n) {
      const int col = cbase + n * 16;
#pragma unroll
      for (int m = 0; m < 4; ++m)
#pragma unroll
        for (int r = 0; r < 4; ++r)
          C[(size_t)(rbase + m * 16 + r) * D_ + col] = (bf16_t)acc[m][n][r];
    }
  }
}

// ---------------------------------------------------------------------------
// Kernel 3: flash attention, swapped-operand 32x32 MFMA, lane-local PV.
// grid 512 blocks (XCD-chunk swizzled: 4 whole heads per XCD), 4 waves x 32
// q-rows, KVBLK=128 = two 64-key subtiles, NT=16. Software-pipelined:
// QK(sub0); QK(sub1); SM+PV(sub0); SM+PV(sub1) — matrix pipe stays busy
// during softmax VALU. exp via v_exp_f32. K swap23 rows; 5-bit swizzle.
// ---------------------------------------------------------------------------
__global__ __launch_bounds__(256) void attn_kernel(
    const bf16_t* __restrict__ Q, const bf16_t* __restrict__ K,
    const bf16_t* __restrict__ Vt, bf16_t* __restrict__ O) {
  constexpr int NT = S_ / 128;
  constexpr float THR = 11.5416f;          // 8 * log2(e)
  __shared__ alignas(16) bf16_t Ks[2][2][64 * 64];
  __shared__ alignas(16) bf16_t Vs[2][2][64 * 64];
  const int t = threadIdx.x, lane = t & 63, wid = t >> 6;
  // XCD-chunk swizzle: 512 blocks = 8 XCDs x 64 = 4 whole heads per XCD.
  const int bid = blockIdx.y * 16 + blockIdx.x;
  const int virt = (bid & 7) * 64 + (bid >> 3);
  const int head = virt >> 4;              // 0..31
  const int b = head >> 4, h = head & 15;
  const int qw = (virt & 15) * 128 + wid * 32;  // this wave's 32 q-rows
  const int q31 = lane & 31, hi = lane >> 5;

  // Q as B-operand frags: col=lane&31=q, k=hi*8+j = d within 16-slice.
  bf16x8 qb[4];
  {
    const size_t qrow = (size_t)(b * S_ + qw + q31) * D_ + h * HD_ + hi * 8;
#pragma unroll
    for (int ksl = 0; ksl < 4; ++ksl) {
      bf16x8 v = *(const bf16x8*)&Q[qrow + ksl * 16];
#pragma unroll
      for (int j = 0; j < 8; ++j)
        v[j] = (bf16_t)((float)v[j] * (0.125f * 1.44269504f));
      qb[ksl] = v;
    }
  }
  bf16x8 onesb;
#pragma unroll
  for (int j = 0; j < 8; ++j) onesb[j] = (bf16_t)1.0f;

  f32x16 ctx0 = {0.f,0.f,0.f,0.f,0.f,0.f,0.f,0.f,0.f,0.f,0.f,0.f,0.f,0.f,0.f,0.f};
  f32x16 ctx1 = ctx0, lf = ctx0;
  float mrow = -1e30f;

  // 5-bit swizzle: logical slot x at row r -> phys (x ^ (r&7) ^ ((r>>3)&3))*8.
  const int srow5 = (q31 & 7) ^ ((q31 >> 3) & 3);
  int sw[4];
#pragma unroll
  for (int x = 0; x < 4; ++x) sw[x] = ((x * 2 + hi) ^ srow5) * 8;

  // staging: wave w, chunk c covers LDS tile-rows c*32 + w*8 + (lane>>3);
  // phys slot (lane&7) holds logical slot (lane&7)^s(trow).
  // K global row = swap23(LDS row) (key permutation, algebra-neutral).
  const int trow = wid * 8 + (lane >> 3);
  const int krow_g = (trow & ~12) | ((trow & 4) << 1) | ((trow & 8) >> 1);
  const int st5 = (trow & 7) ^ ((trow >> 3) & 3);
  const int lslot = ((lane & 7) ^ st5) * 8;
  const bf16_t* Ksrc0 = K + (size_t)(b * S_ + krow_g) * D_ + h * HD_ + lslot;
  const bf16_t* Ksrc1 = K + (size_t)(b * S_ + 32 + krow_g) * D_ + h * HD_ + lslot;
  const bf16_t* Vsrc0 = Vt + (size_t)b * D_ * S_ + (size_t)(h * HD_ + trow) * S_ + lslot;
  const bf16_t* Vsrc1 = Vt + (size_t)b * D_ * S_ + (size_t)(h * HD_ + 32 + trow) * S_ + lslot;

  // prologue: stage tile-pair 0 (subtiles 0 and 1)
#pragma unroll
  for (int sb = 0; sb < 2; ++sb) {
    gload_lds16(Ksrc0 + (size_t)sb * 64 * D_, &Ks[0][sb][wid * 512]);
    gload_lds16(Ksrc1 + (size_t)sb * 64 * D_, &Ks[0][sb][2048 + wid * 512]);
    gload_lds16(Vsrc0 + sb * 64, &Vs[0][sb][wid * 512]);
    gload_lds16(Vsrc1 + sb * 64, &Vs[0][sb][2048 + wid * 512]);
  }

  // QK for one 64-key subtile into (s0, s1)
  auto QK = [&](const bf16_t* Kb, f32x16& s0, f32x16& s1) {
    __builtin_amdgcn_s_setprio(1);
#pragma unroll
    for (int ksl = 0; ksl < 4; ++ksl) {
      bf16x8 kb0 = *(const bf16x8*)&Kb[q31 * 64 + sw[ksl]];
      bf16x8 kb1 = *(const bf16x8*)&Kb[(32 + q31) * 64 + sw[ksl]];
      s0 = mfma32(kb0, qb[ksl], s0);
      s1 = mfma32(kb1, qb[ksl], s1);
    }
    __builtin_amdgcn_s_setprio(0);
  };

  // softmax + P-pack + l/PV accumulate for one subtile
  auto SMPV = [&](f32x16& s0, f32x16& s1, const bf16_t* Vb) {
    float mt = fmaxf(s0[0], s1[0]);
#pragma unroll
    for (int r = 1; r < 16; ++r) mt = fmaxf(fmaxf(mt, s0[r]), s1[r]);
    mt = fmaxf(mt, __shfl_xor(mt, 32));
    if (__any(mt > mrow + THR)) {
      float mnew = fmaxf(mrow, mt);
      float scl = fexp2(mrow - mnew);
      mrow = mnew;
#pragma unroll
      for (int r = 0; r < 16; ++r) {
        float sc = __shfl(scl, (r & 3) + 8 * (r >> 2) + 4 * hi);
        ctx0[r] *= sc; ctx1[r] *= sc; lf[r] *= sc;
      }
    }
#pragma unroll
    for (int r = 0; r < 16; ++r) {
      s0[r] = fexp2(s0[r] - mrow);
      s1[r] = fexp2(s1[r] - mrow);
    }

    bf16x8 pa[4];
#pragma unroll
    for (int ks = 0; ks < 4; ++ks) {
      union { u32 w[4]; bf16x8 v; } u;
      if (ks < 2) {
#pragma unroll
        for (int w = 0; w < 4; ++w)
          u.w[w] = pkbf(s0[(ks & 1) * 8 + 2 * w], s0[(ks & 1) * 8 + 2 * w + 1]);
      } else {
#pragma unroll
        for (int w = 0; w < 4; ++w)
          u.w[w] = pkbf(s1[(ks & 1) * 8 + 2 * w], s1[(ks & 1) * 8 + 2 * w + 1]);
      }
      pa[ks] = u.v;
    }

    __builtin_amdgcn_s_setprio(1);
#pragma unroll
    for (int ks = 0; ks < 4; ++ks) lf = mfma32(pa[ks], onesb, lf);
#pragma unroll
    for (int ks = 0; ks < 4; ++ks) {
      bf16x8 vb0 = *(const bf16x8*)&Vb[q31 * 64 + sw[ks]];
      bf16x8 vb1 = *(const bf16x8*)&Vb[(32 + q31) * 64 + sw[ks]];
      ctx0 = mfma32(pa[ks], vb0, ctx0);
      ctx1 = mfma32(pa[ks], vb1, ctx1);
    }
    __builtin_amdgcn_s_setprio(0);
  };

  for (int kt = 0; kt < NT; ++kt) {
    __syncthreads();                       // tile-pair kt resident
    const int cur = kt & 1, nxt = cur ^ 1;
    if (kt + 1 < NT) {
      const size_t ko = (size_t)(kt + 1) * 128 * D_;
      const size_t vo = (size_t)(kt + 1) * 128;
#pragma unroll
      for (int sb = 0; sb < 2; ++sb) {
        gload_lds16(Ksrc0 + ko + (size_t)sb * 64 * D_, &Ks[nxt][sb][wid * 512]);
        gload_lds16(Ksrc1 + ko + (size_t)sb * 64 * D_, &Ks[nxt][sb][2048 + wid * 512]);
        gload_lds16(Vsrc0 + vo + sb * 64, &Vs[nxt][sb][wid * 512]);
        gload_lds16(Vsrc1 + vo + sb * 64, &Vs[nxt][sb][2048 + wid * 512]);
      }
    }
    // software pipeline: both QK blocks first, then SM+PV pairs.
    f32x16 s0a = {0.f,0.f,0.f,0.f,0.f,0.f,0.f,0.f,0.f,0.f,0.f,0.f,0.f,0.f,0.f,0.f};
    f32x16 s1a = s0a, s0b = s0a, s1b = s0a;
    QK(&Ks[cur][0][0], s0a, s1a);
    QK(&Ks[cur][1][0], s0b, s1b);          // matrix pipe busy during SMPV-a
    SMPV(s0a, s1a, &Vs[cur][0][0]);
    SMPV(s0b, s1b, &Vs[cur][1][0]);
  }

  // epilogue: ctx D-frag row = q = crow(reg,hi), col = d = dchunk*32+(lane&31)
#pragma unroll
  for (int r = 0; r < 16; ++r) {
    const int q = (r & 3) + 8 * (r >> 2) + 4 * hi;
    const float inv = 1.f / lf[r];
    const size_t ro = (size_t)(b * S_ + qw + q) * D_ + h * HD_ + q31;
    O[ro]      = (bf16_t)(ctx0[r] * inv);
    O[ro + 32] = (bf16_t)(ctx1[r] * inv);
  }
}

// ---------------------------------------------------------------------------
// Kernel 4: out = LayerNorm(a + res) * g + b.  a,res bf16; g,b f32.
// ---------------------------------------------------------------------------
template <typename OUT>
__global__ __launch_bounds__(256) void add_ln_kernel(
    const bf16_t* __restrict__ a, const bf16_t* __restrict__ res,
    const float* __restrict__ g, const float* __restrict__ be,
    OUT* __restrict__ out) {
  const int t = threadIdx.x;
  const int d0 = t * 4;
  const size_t base = (size_t)blockIdx.x * D_ + d0;
  bf16x4v av = *(const bf16x4v*)&a[base];
  bf16x4v rv = *(const bf16x4v*)&res[base];
  float x[4];
  float s1 = 0.f, s2 = 0.f;
#pragma unroll
  for (int e = 0; e < 4; ++e) {
    x[e] = (float)av[e] + (float)rv[e];
    s1 += x[e];
    s2 += x[e] * x[e];
  }
#pragma unroll
  for (int o = 32; o > 0; o >>= 1) {
    s1 += __shfl_down(s1, o);
    s2 += __shfl_down(s2, o);
  }
  __shared__ float red[8];
  const int lane = t & 63, wid = t >> 6;
  if (lane == 0) { red[wid] = s1; red[4 + wid] = s2; }
  __syncthreads();
  if (t == 0) {
    float t1 = red[0] + red[1] + red[2] + red[3];
    float t2 = red[4] + red[5] + red[6] + red[7];
    float mu = t1 * (1.f / D_);
    float var = t2 * (1.f / D_) - mu * mu;
    red[0] = mu;
    red[1] = rsqrtf(var + 1e-5f);
  }
  __syncthreads();
  const float mu = red[0], rstd = red[1];
  const float4 gv = *(const float4*)&g[d0];
  const float4 bv = *(const float4*)&be[d0];
  float y[4];
  y[0] = (x[0] - mu) * rstd * gv.x + bv.x;
  y[1] = (x[1] - mu) * rstd * gv.y + bv.y;
  y[2] = (x[2] - mu) * rstd * gv.z + bv.z;
  y[3] = (x[3] - mu) * rstd * gv.w + bv.w;
  if constexpr (sizeof(OUT) == 2) {
    bf16x4v o;
    o[0] = (bf16_t)y[0]; o[1] = (bf16_t)y[1]; o[2] = (bf16_t)y[2]; o[3] = (bf16_t)y[3];
    *(bf16x4v*)&out[base] = o;
  } else {
    float4 o = {y[0], y[1], y[2], y[3]};
    *(float4*)&out[base] = o;
  }
}

// ---------------------------------------------------------------------------
extern "C" void kernel_launch(void* const* d_in, const int* in_sizes, int n_in,
                              void* d_out, int out_size, void* d_ws, size_t ws_size,
                              hipStream_t stream) {
  const float* key   = (const float*)d_in[0];
  const float* value = (const float*)d_in[1];
  const float* query = (const float*)d_in[2];
  const float* Wq = (const float*)d_in[3];
  const float* Wk = (const float*)d_in[4];
  const float* Wv = (const float*)d_in[5];
  const float* Wo = (const float*)d_in[6];
  const float* W1 = (const float*)d_in[7];
  const float* b1 = (const float*)d_in[8];
  const float* W2 = (const float*)d_in[9];
  const float* b2 = (const float*)d_in[10];
  const float* g1 = (const float*)d_in[11];
  const float* be1 = (const float*)d_in[12];
  const float* g2 = (const float*)d_in[13];
  const float* be2 = (const float*)d_in[14];
  float* out = (float*)d_out;

  bf16_t* ws = (bf16_t*)d_ws;
  const size_t NB = (size_t)B_ * S_ * D_;  // 4 Mi elems
  bf16_t* qpe = ws + 0 * NB;
  bf16_t* kpe = ws + 1 * NB;
  bf16_t* vpe = ws + 2 * NB;
  bf16_t* Qp  = ws + 3 * NB;
  bf16_t* Kp  = ws + 4 * NB;
  bf16_t* Vt  = ws + 5 * NB;   // [B][D][S] transposed V projection
  bf16_t* ctx = kpe;  // dead after QKV gemm
  bf16_t* ao  = vpe;  // dead after QKV gemm
  bf16_t* x1  = Qp;   // dead after attention
  bf16_t* hh  = Kp;   // dead after attention
  bf16_t* ff  = Vt;   // dead after attention

  // bf16 weights live in d_out (16 MB; 6 x 2 MB used, overwritten by final LN)
  bf16_t* wb = (bf16_t*)d_out;
  const size_t WN = (size_t)D_ * D_;
  bf16_t* Wqb = wb + 0 * WN;
  bf16_t* Wkb = wb + 1 * WN;
  bf16_t* Wvb = wb + 2 * WN;
  bf16_t* Wob = wb + 3 * WN;
  bf16_t* W1b = wb + 4 * WN;
  bf16_t* W2b = wb + 5 * WN;

  dim3 sgrid(16, 32);                          // 512 blocks (swizzled in-kernel)

  cvtw_kernel<<<dim3(D_ * D_ / 1024, 6), 256, 0, stream>>>(
      Wq, Wk, Wv, Wo, W1, W2, wb);
  addpe_kernel<<<B_ * S_, 256, 0, stream>>>(query, key, value, qpe, kpe, vpe);

  gemm_qkv<<<dim3(8, 32, 3), 256, 0, stream>>>(
      qpe, kpe, vpe, Wqb, Wkb, Wvb, Qp, Kp, Vt);

  attn_kernel<<<dim3(16, 32), 256, 0, stream>>>(Qp, Kp, Vt, ctx);

  gemm_s<0><<<sgrid, 256, 0, stream>>>(ctx, Wob, nullptr, ao);
  add_ln_kernel<bf16_t><<<B_ * S_, 256, 0, stream>>>(ao, qpe, g1, be1, x1);

  gemm_s<2><<<sgrid, 256, 0, stream>>>(x1, W1b, b1, hh);
  gemm_s<1><<<sgrid, 256, 0, stream>>>(hh, W2b, b2, ff);
  add_ln_kernel<float><<<B_ * S_, 256, 0, stream>>>(ff, x1, g2, be2, out);
}

// Round 15
// 192.411 us; speedup vs baseline: 1.1530x; 1.1530x over previous
//
#include <hip/hip_runtime.h>
#include <hip/hip_bf16.h>
#include <math.h>

// ---------------------------------------------------------------------------
// TransformerLayer: B=2 S=2048 D=1024 H=16 HD=64. I/O f32, internals bf16.
// Round 15: attention reverted to r13 exactly (r14's QK-pipeline + attn-XCD
// swizzle both regressed). Singles GEMM: BK=64 = two proven 32-chunks per
// barrier (16 barriers, was 32). qkv/cvtw/addpe/LN unchanged from r13.
// ---------------------------------------------------------------------------

#define B_ 2
#define S_ 2048
#define D_ 1024
#define H_ 16
#define HD_ 64

typedef __bf16 bf16_t;
typedef __bf16 bf16x8 __attribute__((ext_vector_type(8)));
typedef __bf16 bf16x4v __attribute__((ext_vector_type(4)));
typedef float f32x4 __attribute__((ext_vector_type(4)));
typedef float f32x16 __attribute__((ext_vector_type(16)));
typedef unsigned int u32;

__device__ __forceinline__ f32x4 mfma16(bf16x8 a, bf16x8 b, f32x4 c) {
  return __builtin_amdgcn_mfma_f32_16x16x32_bf16(a, b, c, 0, 0, 0);
}
__device__ __forceinline__ f32x16 mfma32(bf16x8 a, bf16x8 b, f32x16 c) {
  return __builtin_amdgcn_mfma_f32_32x32x16_bf16(a, b, c, 0, 0, 0);
}
__device__ __forceinline__ u32 pkbf(float a, float b) {
  union { bf16_t h[2]; u32 u; } t;
  t.h[0] = (bf16_t)a; t.h[1] = (bf16_t)b;
  return t.u;
}
__device__ __forceinline__ float fexp2(float x) {       // single v_exp_f32
  return __builtin_amdgcn_exp2f(x);
}

// global -> LDS direct copy, 16B/lane. LDS dest: wave-uniform base + lane*16.
__device__ __forceinline__ void gload_lds16(const bf16_t* g, bf16_t* l) {
  __builtin_amdgcn_global_load_lds((const __attribute__((address_space(1))) void*)g,
                                   (__attribute__((address_space(3))) void*)l,
                                   16, 0, 0);
}

// ---------------------------------------------------------------------------
// Kernel 0: convert 6 f32 weight matrices (D x D) to bf16, contiguous in dst.
// ---------------------------------------------------------------------------
__global__ __launch_bounds__(256) void cvtw_kernel(
    const float* __restrict__ w0, const float* __restrict__ w1,
    const float* __restrict__ w2, const float* __restrict__ w3,
    const float* __restrict__ w4, const float* __restrict__ w5,
    bf16_t* __restrict__ dst) {
  const int wsel = blockIdx.y;
  const float* src = wsel == 0 ? w0 : wsel == 1 ? w1 : wsel == 2 ? w2
                   : wsel == 3 ? w3 : wsel == 4 ? w4 : w5;
  const size_t off = (size_t)blockIdx.x * 1024 + threadIdx.x * 4;
  float4 v = *(const float4*)(src + off);
  bf16x4v r;
  r[0] = (bf16_t)v.x; r[1] = (bf16_t)v.y; r[2] = (bf16_t)v.z; r[3] = (bf16_t)v.w;
  *(bf16x4v*)(dst + (size_t)wsel * (D_ * D_) + off) = r;
}

// ---------------------------------------------------------------------------
// Kernel 1: positional encoding + add; f32 in -> bf16 out (q,k,v one pass).
// Trig via v_sin/v_cos (revolutions domain + fract range reduction).
// ---------------------------------------------------------------------------
__global__ __launch_bounds__(256) void addpe_kernel(
    const float* __restrict__ q, const float* __restrict__ k,
    const float* __restrict__ v,
    bf16_t* __restrict__ qo, bf16_t* __restrict__ ko, bf16_t* __restrict__ vo) {
  const int row = blockIdx.x;            // b*S + s
  const int s = row & (S_ - 1);
  const int d0 = threadIdx.x * 4;
  const size_t base = (size_t)row * D_ + d0;
  float pe[4];
#pragma unroll
  for (int p = 0; p < 2; ++p) {
    float div = __expf((float)(d0 + 2 * p) * -0.008994473019508f);
    float rev = (float)s * div * 0.15915494309189535f;   // ang / (2*pi)
    float rf = rev - floorf(rev);
    pe[2 * p]     = __builtin_amdgcn_sinf(rf);
    pe[2 * p + 1] = __builtin_amdgcn_cosf(rf);
  }
  float4 qv = *(const float4*)&q[base];
  float4 kv = *(const float4*)&k[base];
  float4 vv = *(const float4*)&v[base];
  bf16x4v qr, kr, vr;
  qr[0] = (bf16_t)(qv.x + pe[0]); qr[1] = (bf16_t)(qv.y + pe[1]);
  qr[2] = (bf16_t)(qv.z + pe[2]); qr[3] = (bf16_t)(qv.w + pe[3]);
  kr[0] = (bf16_t)(kv.x + pe[0]); kr[1] = (bf16_t)(kv.y + pe[1]);
  kr[2] = (bf16_t)(kv.z + pe[2]); kr[3] = (bf16_t)(kv.w + pe[3]);
  vr[0] = (bf16_t)(vv.x + pe[0]); vr[1] = (bf16_t)(vv.y + pe[1]);
  vr[2] = (bf16_t)(vv.z + pe[2]); vr[3] = (bf16_t)(vv.w + pe[3]);
  *(bf16x4v*)&qo[base] = qr;
  *(bf16x4v*)&ko[base] = kr;
  *(bf16x4v*)&vo[base] = vr;
}

// ---------------------------------------------------------------------------
// Kernel 2a: singles NT GEMM, tile 128x64 (512 blocks, XCD-chunk swizzled),
// BK=64 = two 32-chunks per barrier (16 barriers), 4 waves (2x2, each 64x32),
// 2-phase dbuf of chunk-pairs, all-gload_lds.
// EPI: 0 plain, 1 +bias, 2 +bias+relu
// ---------------------------------------------------------------------------
template <int EPI>
__global__ __launch_bounds__(256) void gemm_s(
    const bf16_t* __restrict__ A, const bf16_t* __restrict__ Wb,
    const float* __restrict__ bias, bf16_t* __restrict__ C) {
  constexpr int Kd = 1024, NT2 = Kd / 64;
  __shared__ alignas(16) bf16_t As[2][2][128 * 32];   // [buf][chunk]
  __shared__ alignas(16) bf16_t Bs[2][2][64 * 32];
  const int t = threadIdx.x, lane = t & 63, wid = t >> 6;
  // XCD-chunk swizzle (m204, nwg%8==0): 512 blocks = 8 XCDs x 64.
  const int bid = blockIdx.y * 16 + blockIdx.x;
  const int virt = (bid & 7) * 64 + (bid >> 3);
  const int m0 = (virt >> 4) * 128, n0 = (virt & 15) * 64;

  const bf16_t* Asrc0 = A + (size_t)(m0 + wid * 16 + (lane >> 2)) * Kd + (lane & 3) * 8;
  const bf16_t* Asrc1 = Asrc0 + (size_t)64 * Kd;
  const bf16_t* Wsrc = Wb + (size_t)(n0 + wid * 16 + (lane >> 2)) * Kd + (lane & 3) * 8;

  const f32x4 zero = {0.f, 0.f, 0.f, 0.f};
  f32x4 acc[4][2];
#pragma unroll
  for (int m = 0; m < 4; ++m) { acc[m][0] = zero; acc[m][1] = zero; }

#pragma unroll
  for (int c = 0; c < 2; ++c) {
    gload_lds16(Asrc0 + c * 32, &As[0][c][wid * 512]);
    gload_lds16(Asrc1 + c * 32, &As[0][c][2048 + wid * 512]);
    gload_lds16(Wsrc + c * 32,  &Bs[0][c][wid * 512]);
  }

  const int wr = wid >> 1, wc = wid & 1;
#pragma unroll 2
  for (int kt = 0; kt < NT2; ++kt) {
    __syncthreads();                       // chunk-pair kt resident
    const int cur = kt & 1, nxt = cur ^ 1;
    if (kt + 1 < NT2) {
      const int k0 = (kt + 1) * 64;
#pragma unroll
      for (int c = 0; c < 2; ++c) {
        gload_lds16(Asrc0 + k0 + c * 32, &As[nxt][c][wid * 512]);
        gload_lds16(Asrc1 + k0 + c * 32, &As[nxt][c][2048 + wid * 512]);
        gload_lds16(Wsrc + k0 + c * 32,  &Bs[nxt][c][wid * 512]);
      }
    }
#pragma unroll
    for (int c = 0; c < 2; ++c) {
      bf16x8 af[4], bfr[2];
#pragma unroll
      for (int m = 0; m < 4; ++m)
        af[m] = *(const bf16x8*)&As[cur][c][(wr * 64 + m * 16 + (lane & 15)) * 32 + (lane >> 4) * 8];
#pragma unroll
      for (int n = 0; n < 2; ++n)
        bfr[n] = *(const bf16x8*)&Bs[cur][c][(wc * 32 + n * 16 + (lane & 15)) * 32 + (lane >> 4) * 8];
      __builtin_amdgcn_s_setprio(1);
#pragma unroll
      for (int m = 0; m < 4; ++m)
#pragma unroll
        for (int n = 0; n < 2; ++n)
          acc[m][n] = mfma16(af[m], bfr[n], acc[m][n]);
      __builtin_amdgcn_s_setprio(0);
    }
  }

  const int rbase = m0 + wr * 64 + (lane >> 4) * 4;
  const int cbase = n0 + wc * 32 + (lane & 15);
#pragma unroll
  for (int n = 0; n < 2; ++n) {
    const int col = cbase + n * 16;
    float bv = (EPI >= 1) ? bias[col] : 0.f;
#pragma unroll
    for (int m = 0; m < 4; ++m)
#pragma unroll
      for (int r = 0; r < 4; ++r) {
        float vv = acc[m][n][r] + bv;
        if (EPI == 2) vv = fmaxf(vv, 0.f);
        C[(size_t)(rbase + m * 16 + r) * D_ + col] = (bf16_t)vv;
      }
  }
}

// ---------------------------------------------------------------------------
// Kernel 2b: QKV batched GEMM, tile 128x128 (768 blocks, XCD-chunk swizzled),
// BK=32, 4 waves (2x2, each 64x64), 2-phase dbuf. r9-proven body.
// virt z: 0=Q, 1=K, 2=V^T out (scattered store).
// ---------------------------------------------------------------------------
__global__ __launch_bounds__(256) void gemm_qkv(
    const bf16_t* __restrict__ a0p, const bf16_t* __restrict__ a1p,
    const bf16_t* __restrict__ a2p,
    const bf16_t* __restrict__ w0p, const bf16_t* __restrict__ w1p,
    const bf16_t* __restrict__ w2p,
    bf16_t* __restrict__ o0, bf16_t* __restrict__ o1, bf16_t* __restrict__ o2) {
  constexpr int Kd = 1024, NT = Kd / 32;
  __shared__ alignas(16) bf16_t As[2][128 * 32];
  __shared__ alignas(16) bf16_t Bs[2][128 * 32];
  const int t = threadIdx.x, lane = t & 63, wid = t >> 6;
  const int g = lane >> 4, c16 = lane & 15;
  // XCD-chunk swizzle (m204, nwg%8==0): 768 blocks = 8 XCDs x 96.
  const int bid = blockIdx.z * 256 + blockIdx.y * 8 + blockIdx.x;
  const int virt = (bid & 7) * 96 + (bid >> 3);
  const int zz = virt >> 8;
  const int m0 = ((virt >> 3) & 31) * 128, n0 = (virt & 7) * 128;

  const bf16_t* A = a0p;
  const bf16_t* Wb = w0p;
  if (zz == 1) { A = a1p; Wb = w1p; }
  else if (zz == 2) { A = a2p; Wb = w2p; }

  const bf16_t* Asrc0 = A + (size_t)(m0 + wid * 16 + (lane >> 2)) * Kd + (lane & 3) * 8;
  const bf16_t* Asrc1 = Asrc0 + (size_t)64 * Kd;
  const bf16_t* Wsrc0 = Wb + (size_t)(n0 + wid * 16 + (lane >> 2)) * Kd + (lane & 3) * 8;
  const bf16_t* Wsrc1 = Wsrc0 + (size_t)64 * Kd;

  const f32x4 zero = {0.f, 0.f, 0.f, 0.f};
  f32x4 acc[4][4];
#pragma unroll
  for (int m = 0; m < 4; ++m)
#pragma unroll
    for (int n = 0; n < 4; ++n) acc[m][n] = zero;

  gload_lds16(Asrc0, &As[0][wid * 512]);
  gload_lds16(Asrc1, &As[0][2048 + wid * 512]);
  gload_lds16(Wsrc0, &Bs[0][wid * 512]);
  gload_lds16(Wsrc1, &Bs[0][2048 + wid * 512]);

  const int wr = wid >> 1, wc = wid & 1;
#pragma unroll 2
  for (int kt = 0; kt < NT; ++kt) {
    __syncthreads();
    const int cur = kt & 1, nxt = cur ^ 1;
    if (kt + 1 < NT) {
      const int k0 = (kt + 1) * 32;
      gload_lds16(Asrc0 + k0, &As[nxt][wid * 512]);
      gload_lds16(Asrc1 + k0, &As[nxt][2048 + wid * 512]);
      gload_lds16(Wsrc0 + k0, &Bs[nxt][wid * 512]);
      gload_lds16(Wsrc1 + k0, &Bs[nxt][2048 + wid * 512]);
    }
    bf16x8 af[4], bfr[4];
#pragma unroll
    for (int m = 0; m < 4; ++m)
      af[m] = *(const bf16x8*)&As[cur][(wr * 64 + m * 16 + c16) * 32 + g * 8];
#pragma unroll
    for (int n = 0; n < 4; ++n)
      bfr[n] = *(const bf16x8*)&Bs[cur][(wc * 64 + n * 16 + c16) * 32 + g * 8];
    __builtin_amdgcn_s_setprio(1);
#pragma unroll
    for (int m = 0; m < 4; ++m)
#pragma unroll
      for (int n = 0; n < 4; ++n)
        acc[m][n] = mfma16(af[m], bfr[n], acc[m][n]);
    __builtin_amdgcn_s_setprio(0);
  }

  const int rbase = m0 + wr * 64 + g * 4;
  const int cbase = n0 + wc * 64 + c16;
  if (zz == 2) {
#pragma unroll
    for (int n = 0; n < 4; ++n) {
      const int col = cbase + n * 16;
#pragma unroll
      for (int m = 0; m < 4; ++m)
#pragma unroll
        for (int r = 0; r < 4; ++r) {
          const int row = rbase + m * 16 + r;
          const int bb = row >> 11, ss = row & (S_ - 1);
          o2[(size_t)bb * D_ * S_ + (size_t)col * S_ + ss] = (bf16_t)acc[m][n][r];
        }
    }
  } else {
    bf16_t* C = (zz == 1) ? o1 : o0;
#pragma unroll
    for (int n = 0; n < 4; ++n) {
      const int col = cbase + n * 16;
#pragma unroll
      for (int m = 0; m < 4; ++m)
#pragma unroll
        for (int r = 0; r < 4; ++r)
          C[(size_t)(rbase + m * 16 + r) * D_ + col] = (bf16_t)acc[m][n][r];
    }
  }
}

// ---------------------------------------------------------------------------
// Kernel 3: flash attention (r13 version). Swapped-operand 32x32 MFMA,
// lane-local PV. grid (S/128, B*H), 4 waves x 32 q-rows, KVBLK=128 = two
// 64-key subtiles per barrier, NT=16. exp via v_exp_f32. K swap23 rows;
// 5-bit swizzle s(row)=(row&7)^((row>>3)&3) -> conflict-free b128 reads.
// ---------------------------------------------------------------------------
__global__ __launch_bounds__(256) void attn_kernel(
    const bf16_t* __restrict__ Q, const bf16_t* __restrict__ K,
    const bf16_t* __restrict__ Vt, bf16_t* __restrict__ O) {
  constexpr int NT = S_ / 128;
  constexpr float THR = 11.5416f;          // 8 * log2(e)
  __shared__ alignas(16) bf16_t Ks[2][2][64 * 64];
  __shared__ alignas(16) bf16_t Vs[2][2][64 * 64];
  const int t = threadIdx.x, lane = t & 63, wid = t >> 6;
  const int b = blockIdx.y >> 4, h = blockIdx.y & 15;
  const int qw = blockIdx.x * 128 + wid * 32;   // this wave's 32 q-rows
  const int q31 = lane & 31, hi = lane >> 5;

  // Q as B-operand frags: col=lane&31=q, k=hi*8+j = d within 16-slice.
  bf16x8 qb[4];
  {
    const size_t qrow = (size_t)(b * S_ + qw + q31) * D_ + h * HD_ + hi * 8;
#pragma unroll
    for (int ksl = 0; ksl < 4; ++ksl) {
      bf16x8 v = *(const bf16x8*)&Q[qrow + ksl * 16];
#pragma unroll
      for (int j = 0; j < 8; ++j)
        v[j] = (bf16_t)((float)v[j] * (0.125f * 1.44269504f));
      qb[ksl] = v;
    }
  }
  bf16x8 onesb;
#pragma unroll
  for (int j = 0; j < 8; ++j) onesb[j] = (bf16_t)1.0f;

  f32x16 ctx0 = {0.f,0.f,0.f,0.f,0.f,0.f,0.f,0.f,0.f,0.f,0.f,0.f,0.f,0.f,0.f,0.f};
  f32x16 ctx1 = ctx0, lf = ctx0;
  float mrow = -1e30f;

  // 5-bit swizzle: logical slot x at row r -> phys (x ^ (r&7) ^ ((r>>3)&3))*8.
  const int srow5 = (q31 & 7) ^ ((q31 >> 3) & 3);
  int sw[4];
#pragma unroll
  for (int x = 0; x < 4; ++x) sw[x] = ((x * 2 + hi) ^ srow5) * 8;

  // staging: wave w, chunk c covers LDS tile-rows c*32 + w*8 + (lane>>3);
  // phys slot (lane&7) holds logical slot (lane&7)^s(trow).
  // K global row = swap23(LDS row) (key permutation, algebra-neutral).
  const int trow = wid * 8 + (lane >> 3);
  const int krow_g = (trow & ~12) | ((trow & 4) << 1) | ((trow & 8) >> 1);
  const int st5 = (trow & 7) ^ ((trow >> 3) & 3);
  const int lslot = ((lane & 7) ^ st5) * 8;
  const bf16_t* Ksrc0 = K + (size_t)(b * S_ + krow_g) * D_ + h * HD_ + lslot;
  const bf16_t* Ksrc1 = K + (size_t)(b * S_ + 32 + krow_g) * D_ + h * HD_ + lslot;
  const bf16_t* Vsrc0 = Vt + (size_t)b * D_ * S_ + (size_t)(h * HD_ + trow) * S_ + lslot;
  const bf16_t* Vsrc1 = Vt + (size_t)b * D_ * S_ + (size_t)(h * HD_ + 32 + trow) * S_ + lslot;

  // prologue: stage tile-pair 0 (subtiles 0 and 1)
#pragma unroll
  for (int sb = 0; sb < 2; ++sb) {
    gload_lds16(Ksrc0 + (size_t)sb * 64 * D_, &Ks[0][sb][wid * 512]);
    gload_lds16(Ksrc1 + (size_t)sb * 64 * D_, &Ks[0][sb][2048 + wid * 512]);
    gload_lds16(Vsrc0 + sb * 64, &Vs[0][sb][wid * 512]);
    gload_lds16(Vsrc1 + sb * 64, &Vs[0][sb][2048 + wid * 512]);
  }

  // one 64-key subtile: QK^T + softmax + P-pack + l/PV accumulate
  auto SUB = [&](const bf16_t* Kb, const bf16_t* Vb) {
    f32x16 s0 = {0.f,0.f,0.f,0.f,0.f,0.f,0.f,0.f,0.f,0.f,0.f,0.f,0.f,0.f,0.f,0.f};
    f32x16 s1 = s0;
    __builtin_amdgcn_s_setprio(1);
#pragma unroll
    for (int ksl = 0; ksl < 4; ++ksl) {
      bf16x8 kb0 = *(const bf16x8*)&Kb[q31 * 64 + sw[ksl]];
      bf16x8 kb1 = *(const bf16x8*)&Kb[(32 + q31) * 64 + sw[ksl]];
      s0 = mfma32(kb0, qb[ksl], s0);
      s1 = mfma32(kb1, qb[ksl], s1);
    }
    __builtin_amdgcn_s_setprio(0);

    float mt = fmaxf(s0[0], s1[0]);
#pragma unroll
    for (int r = 1; r < 16; ++r) mt = fmaxf(fmaxf(mt, s0[r]), s1[r]);
    mt = fmaxf(mt, __shfl_xor(mt, 32));
    if (__any(mt > mrow + THR)) {
      float mnew = fmaxf(mrow, mt);
      float scl = fexp2(mrow - mnew);
      mrow = mnew;
#pragma unroll
      for (int r = 0; r < 16; ++r) {
        float sc = __shfl(scl, (r & 3) + 8 * (r >> 2) + 4 * hi);
        ctx0[r] *= sc; ctx1[r] *= sc; lf[r] *= sc;
      }
    }
#pragma unroll
    for (int r = 0; r < 16; ++r) {
      s0[r] = fexp2(s0[r] - mrow);
      s1[r] = fexp2(s1[r] - mrow);
    }

    bf16x8 pa[4];
#pragma unroll
    for (int ks = 0; ks < 4; ++ks) {
      union { u32 w[4]; bf16x8 v; } u;
      if (ks < 2) {
#pragma unroll
        for (int w = 0; w < 4; ++w)
          u.w[w] = pkbf(s0[(ks & 1) * 8 + 2 * w], s0[(ks & 1) * 8 + 2 * w + 1]);
      } else {
#pragma unroll
        for (int w = 0; w < 4; ++w)
          u.w[w] = pkbf(s1[(ks & 1) * 8 + 2 * w], s1[(ks & 1) * 8 + 2 * w + 1]);
      }
      pa[ks] = u.v;
    }

    __builtin_amdgcn_s_setprio(1);
#pragma unroll
    for (int ks = 0; ks < 4; ++ks) lf = mfma32(pa[ks], onesb, lf);
#pragma unroll
    for (int ks = 0; ks < 4; ++ks) {
      bf16x8 vb0 = *(const bf16x8*)&Vb[q31 * 64 + sw[ks]];
      bf16x8 vb1 = *(const bf16x8*)&Vb[(32 + q31) * 64 + sw[ks]];
      ctx0 = mfma32(pa[ks], vb0, ctx0);
      ctx1 = mfma32(pa[ks], vb1, ctx1);
    }
    __builtin_amdgcn_s_setprio(0);
  };

  for (int kt = 0; kt < NT; ++kt) {
    __syncthreads();                       // tile-pair kt resident
    const int cur = kt & 1, nxt = cur ^ 1;
    if (kt + 1 < NT) {
      const size_t ko = (size_t)(kt + 1) * 128 * D_;
      const size_t vo = (size_t)(kt + 1) * 128;
#pragma unroll
      for (int sb = 0; sb < 2; ++sb) {
        gload_lds16(Ksrc0 + ko + (size_t)sb * 64 * D_, &Ks[nxt][sb][wid * 512]);
        gload_lds16(Ksrc1 + ko + (size_t)sb * 64 * D_, &Ks[nxt][sb][2048 + wid * 512]);
        gload_lds16(Vsrc0 + vo + sb * 64, &Vs[nxt][sb][wid * 512]);
        gload_lds16(Vsrc1 + vo + sb * 64, &Vs[nxt][sb][2048 + wid * 512]);
      }
    }
    SUB(&Ks[cur][0][0], &Vs[cur][0][0]);
    SUB(&Ks[cur][1][0], &Vs[cur][1][0]);
  }

  // epilogue: ctx D-frag row = q = crow(reg,hi), col = d = dchunk*32+(lane&31)
#pragma unroll
  for (int r = 0; r < 16; ++r) {
    const int q = (r & 3) + 8 * (r >> 2) + 4 * hi;
    const float inv = 1.f / lf[r];
    const size_t ro = (size_t)(b * S_ + qw + q) * D_ + h * HD_ + q31;
    O[ro]      = (bf16_t)(ctx0[r] * inv);
    O[ro + 32] = (bf16_t)(ctx1[r] * inv);
  }
}

// ---------------------------------------------------------------------------
// Kernel 4: out = LayerNorm(a + res) * g + b.  a,res bf16; g,b f32.
// ---------------------------------------------------------------------------
template <typename OUT>
__global__ __launch_bounds__(256) void add_ln_kernel(
    const bf16_t* __restrict__ a, const bf16_t* __restrict__ res,
    const float* __restrict__ g, const float* __restrict__ be,
    OUT* __restrict__ out) {
  const int t = threadIdx.x;
  const int d0 = t * 4;
  const size_t base = (size_t)blockIdx.x * D_ + d0;
  bf16x4v av = *(const bf16x4v*)&a[base];
  bf16x4v rv = *(const bf16x4v*)&res[base];
  float x[4];
  float s1 = 0.f, s2 = 0.f;
#pragma unroll
  for (int e = 0; e < 4; ++e) {
    x[e] = (float)av[e] + (float)rv[e];
    s1 += x[e];
    s2 += x[e] * x[e];
  }
#pragma unroll
  for (int o = 32; o > 0; o >>= 1) {
    s1 += __shfl_down(s1, o);
    s2 += __shfl_down(s2, o);
  }
  __shared__ float red[8];
  const int lane = t & 63, wid = t >> 6;
  if (lane == 0) { red[wid] = s1; red[4 + wid] = s2; }
  __syncthreads();
  if (t == 0) {
    float t1 = red[0] + red[1] + red[2] + red[3];
    float t2 = red[4] + red[5] + red[6] + red[7];
    float mu = t1 * (1.f / D_);
    float var = t2 * (1.f / D_) - mu * mu;
    red[0] = mu;
    red[1] = rsqrtf(var + 1e-5f);
  }
  __syncthreads();
  const float mu = red[0], rstd = red[1];
  const float4 gv = *(const float4*)&g[d0];
  const float4 bv = *(const float4*)&be[d0];
  float y[4];
  y[0] = (x[0] - mu) * rstd * gv.x + bv.x;
  y[1] = (x[1] - mu) * rstd * gv.y + bv.y;
  y[2] = (x[2] - mu) * rstd * gv.z + bv.z;
  y[3] = (x[3] - mu) * rstd * gv.w + bv.w;
  if constexpr (sizeof(OUT) == 2) {
    bf16x4v o;
    o[0] = (bf16_t)y[0]; o[1] = (bf16_t)y[1]; o[2] = (bf16_t)y[2]; o[3] = (bf16_t)y[3];
    *(bf16x4v*)&out[base] = o;
  } else {
    float4 o = {y[0], y[1], y[2], y[3]};
    *(float4*)&out[base] = o;
  }
}

// ---------------------------------------------------------------------------
extern "C" void kernel_launch(void* const* d_in, const int* in_sizes, int n_in,
                              void* d_out, int out_size, void* d_ws, size_t ws_size,
                              hipStream_t stream) {
  const float* key   = (const float*)d_in[0];
  const float* value = (const float*)d_in[1];
  const float* query = (const float*)d_in[2];
  const float* Wq = (const float*)d_in[3];
  const float* Wk = (const float*)d_in[4];
  const float* Wv = (const float*)d_in[5];
  const float* Wo = (const float*)d_in[6];
  const float* W1 = (const float*)d_in[7];
  const float* b1 = (const float*)d_in[8];
  const float* W2 = (const float*)d_in[9];
  const float* b2 = (const float*)d_in[10];
  const float* g1 = (const float*)d_in[11];
  const float* be1 = (const float*)d_in[12];
  const float* g2 = (const float*)d_in[13];
  const float* be2 = (const float*)d_in[14];
  float* out = (float*)d_out;

  bf16_t* ws = (bf16_t*)d_ws;
  const size_t NB = (size_t)B_ * S_ * D_;  // 4 Mi elems
  bf16_t* qpe = ws + 0 * NB;
  bf16_t* kpe = ws + 1 * NB;
  bf16_t* vpe = ws + 2 * NB;
  bf16_t* Qp  = ws + 3 * NB;
  bf16_t* Kp  = ws + 4 * NB;
  bf16_t* Vt  = ws + 5 * NB;   // [B][D][S] transposed V projection
  bf16_t* ctx = kpe;  // dead after QKV gemm
  bf16_t* ao  = vpe;  // dead after QKV gemm
  bf16_t* x1  = Qp;   // dead after attention
  bf16_t* hh  = Kp;   // dead after attention
  bf16_t* ff  = Vt;   // dead after attention

  // bf16 weights live in d_out (16 MB; 6 x 2 MB used, overwritten by final LN)
  bf16_t* wb = (bf16_t*)d_out;
  const size_t WN = (size_t)D_ * D_;
  bf16_t* Wqb = wb + 0 * WN;
  bf16_t* Wkb = wb + 1 * WN;
  bf16_t* Wvb = wb + 2 * WN;
  bf16_t* Wob = wb + 3 * WN;
  bf16_t* W1b = wb + 4 * WN;
  bf16_t* W2b = wb + 5 * WN;

  dim3 sgrid(16, 32);                          // 512 blocks (swizzled in-kernel)

  cvtw_kernel<<<dim3(D_ * D_ / 1024, 6), 256, 0, stream>>>(
      Wq, Wk, Wv, Wo, W1, W2, wb);
  addpe_kernel<<<B_ * S_, 256, 0, stream>>>(query, key, value, qpe, kpe, vpe);

  gemm_qkv<<<dim3(8, 32, 3), 256, 0, stream>>>(
      qpe, kpe, vpe, Wqb, Wkb, Wvb, Qp, Kp, Vt);

  attn_kernel<<<dim3(S_ / 128, B_ * H_), 256, 0, stream>>>(Qp, Kp, Vt, ctx);

  gemm_s<0><<<sgrid, 256, 0, stream>>>(ctx, Wob, nullptr, ao);
  add_ln_kernel<bf16_t><<<B_ * S_, 256, 0, stream>>>(ao, qpe, g1, be1, x1);

  gemm_s<2><<<sgrid, 256, 0, stream>>>(x1, W1b, b1, hh);
  gemm_s<1><<<sgrid, 256, 0, stream>>>(hh, W2b, b2, ff);
  add_ln_kernel<float><<<B_ * S_, 256, 0, stream>>>(ff, x1, g2, be2, out);
}

// Round 16
// 190.510 us; speedup vs baseline: 1.1645x; 1.0100x over previous
//
#include <hip/hip_runtime.h>
#include <hip/hip_bf16.h>
#include <math.h>

// ---------------------------------------------------------------------------
// TransformerLayer: B=2 S=2048 D=1024 H=16 HD=64. I/O f32, internals bf16.
// Round 16: r15 + coalesced V^T epilogue in gemm_qkv via LDS transpose bounce
// using the NAMED As/Bs arrays (wave-uniform wc selects the array; no smem
// union / pointer-array indexing — the r11 abort suspect). Everything else
// byte-identical to r15 (192.4 us).
// ---------------------------------------------------------------------------

#define B_ 2
#define S_ 2048
#define D_ 1024
#define H_ 16
#define HD_ 64

typedef __bf16 bf16_t;
typedef __bf16 bf16x8 __attribute__((ext_vector_type(8)));
typedef __bf16 bf16x4v __attribute__((ext_vector_type(4)));
typedef float f32x4 __attribute__((ext_vector_type(4)));
typedef float f32x16 __attribute__((ext_vector_type(16)));
typedef unsigned int u32;

__device__ __forceinline__ f32x4 mfma16(bf16x8 a, bf16x8 b, f32x4 c) {
  return __builtin_amdgcn_mfma_f32_16x16x32_bf16(a, b, c, 0, 0, 0);
}
__device__ __forceinline__ f32x16 mfma32(bf16x8 a, bf16x8 b, f32x16 c) {
  return __builtin_amdgcn_mfma_f32_32x32x16_bf16(a, b, c, 0, 0, 0);
}
__device__ __forceinline__ u32 pkbf(float a, float b) {
  union { bf16_t h[2]; u32 u; } t;
  t.h[0] = (bf16_t)a; t.h[1] = (bf16_t)b;
  return t.u;
}
__device__ __forceinline__ float fexp2(float x) {       // single v_exp_f32
  return __builtin_amdgcn_exp2f(x);
}

// global -> LDS direct copy, 16B/lane. LDS dest: wave-uniform base + lane*16.
__device__ __forceinline__ void gload_lds16(const bf16_t* g, bf16_t* l) {
  __builtin_amdgcn_global_load_lds((const __attribute__((address_space(1))) void*)g,
                                   (__attribute__((address_space(3))) void*)l,
                                   16, 0, 0);
}

// ---------------------------------------------------------------------------
// Kernel 0: convert 6 f32 weight matrices (D x D) to bf16, contiguous in dst.
// ---------------------------------------------------------------------------
__global__ __launch_bounds__(256) void cvtw_kernel(
    const float* __restrict__ w0, const float* __restrict__ w1,
    const float* __restrict__ w2, const float* __restrict__ w3,
    const float* __restrict__ w4, const float* __restrict__ w5,
    bf16_t* __restrict__ dst) {
  const int wsel = blockIdx.y;
  const float* src = wsel == 0 ? w0 : wsel == 1 ? w1 : wsel == 2 ? w2
                   : wsel == 3 ? w3 : wsel == 4 ? w4 : w5;
  const size_t off = (size_t)blockIdx.x * 1024 + threadIdx.x * 4;
  float4 v = *(const float4*)(src + off);
  bf16x4v r;
  r[0] = (bf16_t)v.x; r[1] = (bf16_t)v.y; r[2] = (bf16_t)v.z; r[3] = (bf16_t)v.w;
  *(bf16x4v*)(dst + (size_t)wsel * (D_ * D_) + off) = r;
}

// ---------------------------------------------------------------------------
// Kernel 1: positional encoding + add; f32 in -> bf16 out (q,k,v one pass).
// Trig via v_sin/v_cos (revolutions domain + fract range reduction).
// ---------------------------------------------------------------------------
__global__ __launch_bounds__(256) void addpe_kernel(
    const float* __restrict__ q, const float* __restrict__ k,
    const float* __restrict__ v,
    bf16_t* __restrict__ qo, bf16_t* __restrict__ ko, bf16_t* __restrict__ vo) {
  const int row = blockIdx.x;            // b*S + s
  const int s = row & (S_ - 1);
  const int d0 = threadIdx.x * 4;
  const size_t base = (size_t)row * D_ + d0;
  float pe[4];
#pragma unroll
  for (int p = 0; p < 2; ++p) {
    float div = __expf((float)(d0 + 2 * p) * -0.008994473019508f);
    float rev = (float)s * div * 0.15915494309189535f;   // ang / (2*pi)
    float rf = rev - floorf(rev);
    pe[2 * p]     = __builtin_amdgcn_sinf(rf);
    pe[2 * p + 1] = __builtin_amdgcn_cosf(rf);
  }
  float4 qv = *(const float4*)&q[base];
  float4 kv = *(const float4*)&k[base];
  float4 vv = *(const float4*)&v[base];
  bf16x4v qr, kr, vr;
  qr[0] = (bf16_t)(qv.x + pe[0]); qr[1] = (bf16_t)(qv.y + pe[1]);
  qr[2] = (bf16_t)(qv.z + pe[2]); qr[3] = (bf16_t)(qv.w + pe[3]);
  kr[0] = (bf16_t)(kv.x + pe[0]); kr[1] = (bf16_t)(kv.y + pe[1]);
  kr[2] = (bf16_t)(kv.z + pe[2]); kr[3] = (bf16_t)(kv.w + pe[3]);
  vr[0] = (bf16_t)(vv.x + pe[0]); vr[1] = (bf16_t)(vv.y + pe[1]);
  vr[2] = (bf16_t)(vv.z + pe[2]); vr[3] = (bf16_t)(vv.w + pe[3]);
  *(bf16x4v*)&qo[base] = qr;
  *(bf16x4v*)&ko[base] = kr;
  *(bf16x4v*)&vo[base] = vr;
}

// ---------------------------------------------------------------------------
// Kernel 2a: singles NT GEMM, tile 128x64 (512 blocks, XCD-chunk swizzled),
// BK=64 = two 32-chunks per barrier (16 barriers), 4 waves (2x2, each 64x32),
// 2-phase dbuf of chunk-pairs, all-gload_lds.
// EPI: 0 plain, 1 +bias, 2 +bias+relu
// ---------------------------------------------------------------------------
template <int EPI>
__global__ __launch_bounds__(256) void gemm_s(
    const bf16_t* __restrict__ A, const bf16_t* __restrict__ Wb,
    const float* __restrict__ bias, bf16_t* __restrict__ C) {
  constexpr int Kd = 1024, NT2 = Kd / 64;
  __shared__ alignas(16) bf16_t As[2][2][128 * 32];   // [buf][chunk]
  __shared__ alignas(16) bf16_t Bs[2][2][64 * 32];
  const int t = threadIdx.x, lane = t & 63, wid = t >> 6;
  // XCD-chunk swizzle (m204, nwg%8==0): 512 blocks = 8 XCDs x 64.
  const int bid = blockIdx.y * 16 + blockIdx.x;
  const int virt = (bid & 7) * 64 + (bid >> 3);
  const int m0 = (virt >> 4) * 128, n0 = (virt & 15) * 64;

  const bf16_t* Asrc0 = A + (size_t)(m0 + wid * 16 + (lane >> 2)) * Kd + (lane & 3) * 8;
  const bf16_t* Asrc1 = Asrc0 + (size_t)64 * Kd;
  const bf16_t* Wsrc = Wb + (size_t)(n0 + wid * 16 + (lane >> 2)) * Kd + (lane & 3) * 8;

  const f32x4 zero = {0.f, 0.f, 0.f, 0.f};
  f32x4 acc[4][2];
#pragma unroll
  for (int m = 0; m < 4; ++m) { acc[m][0] = zero; acc[m][1] = zero; }

#pragma unroll
  for (int c = 0; c < 2; ++c) {
    gload_lds16(Asrc0 + c * 32, &As[0][c][wid * 512]);
    gload_lds16(Asrc1 + c * 32, &As[0][c][2048 + wid * 512]);
    gload_lds16(Wsrc + c * 32,  &Bs[0][c][wid * 512]);
  }

  const int wr = wid >> 1, wc = wid & 1;
#pragma unroll 2
  for (int kt = 0; kt < NT2; ++kt) {
    __syncthreads();                       // chunk-pair kt resident
    const int cur = kt & 1, nxt = cur ^ 1;
    if (kt + 1 < NT2) {
      const int k0 = (kt + 1) * 64;
#pragma unroll
      for (int c = 0; c < 2; ++c) {
        gload_lds16(Asrc0 + k0 + c * 32, &As[nxt][c][wid * 512]);
        gload_lds16(Asrc1 + k0 + c * 32, &As[nxt][c][2048 + wid * 512]);
        gload_lds16(Wsrc + k0 + c * 32,  &Bs[nxt][c][wid * 512]);
      }
    }
#pragma unroll
    for (int c = 0; c < 2; ++c) {
      bf16x8 af[4], bfr[2];
#pragma unroll
      for (int m = 0; m < 4; ++m)
        af[m] = *(const bf16x8*)&As[cur][c][(wr * 64 + m * 16 + (lane & 15)) * 32 + (lane >> 4) * 8];
#pragma unroll
      for (int n = 0; n < 2; ++n)
        bfr[n] = *(const bf16x8*)&Bs[cur][c][(wc * 32 + n * 16 + (lane & 15)) * 32 + (lane >> 4) * 8];
      __builtin_amdgcn_s_setprio(1);
#pragma unroll
      for (int m = 0; m < 4; ++m)
#pragma unroll
        for (int n = 0; n < 2; ++n)
          acc[m][n] = mfma16(af[m], bfr[n], acc[m][n]);
      __builtin_amdgcn_s_setprio(0);
    }
  }

  const int rbase = m0 + wr * 64 + (lane >> 4) * 4;
  const int cbase = n0 + wc * 32 + (lane & 15);
#pragma unroll
  for (int n = 0; n < 2; ++n) {
    const int col = cbase + n * 16;
    float bv = (EPI >= 1) ? bias[col] : 0.f;
#pragma unroll
    for (int m = 0; m < 4; ++m)
#pragma unroll
      for (int r = 0; r < 4; ++r) {
        float vv = acc[m][n][r] + bv;
        if (EPI == 2) vv = fmaxf(vv, 0.f);
        C[(size_t)(rbase + m * 16 + r) * D_ + col] = (bf16_t)vv;
      }
  }
}

// ---------------------------------------------------------------------------
// Kernel 2b: QKV batched GEMM, tile 128x128 (768 blocks, XCD-chunk swizzled),
// BK=32, 4 waves (2x2, each 64x64), 2-phase dbuf. r9-proven staging/K-loop.
// virt z: 0=Q, 1=K (direct stores); 2=V^T via LDS transpose bounce reusing
// the named As (d<64) / Bs (d>=64) arrays -> coalesced bf16x8 stores along s.
// ---------------------------------------------------------------------------
__global__ __launch_bounds__(256) void gemm_qkv(
    const bf16_t* __restrict__ a0p, const bf16_t* __restrict__ a1p,
    const bf16_t* __restrict__ a2p,
    const bf16_t* __restrict__ w0p, const bf16_t* __restrict__ w1p,
    const bf16_t* __restrict__ w2p,
    bf16_t* __restrict__ o0, bf16_t* __restrict__ o1, bf16_t* __restrict__ o2) {
  constexpr int Kd = 1024, NT = Kd / 32;
  __shared__ alignas(16) bf16_t As[2][128 * 32];
  __shared__ alignas(16) bf16_t Bs[2][128 * 32];
  const int t = threadIdx.x, lane = t & 63, wid = t >> 6;
  const int g = lane >> 4, c16 = lane & 15;
  // XCD-chunk swizzle (m204, nwg%8==0): 768 blocks = 8 XCDs x 96.
  const int bid = blockIdx.z * 256 + blockIdx.y * 8 + blockIdx.x;
  const int virt = (bid & 7) * 96 + (bid >> 3);
  const int zz = virt >> 8;
  const int m0 = ((virt >> 3) & 31) * 128, n0 = (virt & 7) * 128;

  const bf16_t* A = a0p;
  const bf16_t* Wb = w0p;
  if (zz == 1) { A = a1p; Wb = w1p; }
  else if (zz == 2) { A = a2p; Wb = w2p; }

  const bf16_t* Asrc0 = A + (size_t)(m0 + wid * 16 + (lane >> 2)) * Kd + (lane & 3) * 8;
  const bf16_t* Asrc1 = Asrc0 + (size_t)64 * Kd;
  const bf16_t* Wsrc0 = Wb + (size_t)(n0 + wid * 16 + (lane >> 2)) * Kd + (lane & 3) * 8;
  const bf16_t* Wsrc1 = Wsrc0 + (size_t)64 * Kd;

  const f32x4 zero = {0.f, 0.f, 0.f, 0.f};
  f32x4 acc[4][4];
#pragma unroll
  for (int m = 0; m < 4; ++m)
#pragma unroll
    for (int n = 0; n < 4; ++n) acc[m][n] = zero;

  gload_lds16(Asrc0, &As[0][wid * 512]);
  gload_lds16(Asrc1, &As[0][2048 + wid * 512]);
  gload_lds16(Wsrc0, &Bs[0][wid * 512]);
  gload_lds16(Wsrc1, &Bs[0][2048 + wid * 512]);

  const int wr = wid >> 1, wc = wid & 1;
#pragma unroll 2
  for (int kt = 0; kt < NT; ++kt) {
    __syncthreads();
    const int cur = kt & 1, nxt = cur ^ 1;
    if (kt + 1 < NT) {
      const int k0 = (kt + 1) * 32;
      gload_lds16(Asrc0 + k0, &As[nxt][wid * 512]);
      gload_lds16(Asrc1 + k0, &As[nxt][2048 + wid * 512]);
      gload_lds16(Wsrc0 + k0, &Bs[nxt][wid * 512]);
      gload_lds16(Wsrc1 + k0, &Bs[nxt][2048 + wid * 512]);
    }
    bf16x8 af[4], bfr[4];
#pragma unroll
    for (int m = 0; m < 4; ++m)
      af[m] = *(const bf16x8*)&As[cur][(wr * 64 + m * 16 + c16) * 32 + g * 8];
#pragma unroll
    for (int n = 0; n < 4; ++n)
      bfr[n] = *(const bf16x8*)&Bs[cur][(wc * 64 + n * 16 + c16) * 32 + g * 8];
    __builtin_amdgcn_s_setprio(1);
#pragma unroll
    for (int m = 0; m < 4; ++m)
#pragma unroll
      for (int n = 0; n < 4; ++n)
        acc[m][n] = mfma16(af[m], bfr[n], acc[m][n]);
    __builtin_amdgcn_s_setprio(0);
  }

  const int rbase = m0 + wr * 64 + g * 4;
  const int cbase = n0 + wc * 64 + c16;
  if (zz == 2) {
    // V^T transpose bounce. Tile is 128 d-cols x 128 s-rows; store s-major
    // [d_l][s_l] with bank swizzle s_l ^= (d_l&7)<<4. d_l<64 -> As, else Bs
    // (wave-uniform: wc). All waves' last LDS reads completed first.
    __syncthreads();
#pragma unroll
    for (int n = 0; n < 4; ++n) {
      const int d_l = wc * 64 + n * 16 + c16;   // 0..127
      const int dl6 = n * 16 + c16;             // d_l & 63
      const int sxh = (d_l & 7) << 4;
      bf16_t* const half = wc ? &Bs[0][0] : &As[0][0];
#pragma unroll
      for (int m = 0; m < 4; ++m) {
        const int s_l = (wr * 64 + g * 4 + m * 16) ^ sxh;   // 4-aligned
        u32* p = (u32*)&half[dl6 * 128 + s_l];
        p[0] = pkbf(acc[m][n][0], acc[m][n][1]);
        p[1] = pkbf(acc[m][n][2], acc[m][n][3]);
      }
    }
    __syncthreads();
    const int bb = m0 >> 11;
    const int sbase = m0 & (S_ - 1);
    const size_t obase = (size_t)bb * D_ * S_ + sbase;
#pragma unroll
    for (int p = 0; p < 8; ++p) {
      const int d_l = p * 16 + (t >> 4);        // 0..127
      const bf16_t* const hr = (p < 4) ? &As[0][0] : &Bs[0][0];
      const int dl6 = d_l & 63;
      const int s0i = (t & 15) * 8;
      const int sx = s0i ^ ((d_l & 7) << 4);
      bf16x8 v = *(const bf16x8*)&hr[dl6 * 128 + sx];
      *(bf16x8*)&o2[obase + (size_t)(n0 + d_l) * S_ + s0i] = v;
    }
  } else {
    bf16_t* C = (zz == 1) ? o1 : o0;
#pragma unroll
    for (int n = 0; n < 4; ++n) {
      const int col = cbase + n * 16;
#pragma unroll
      for (int m = 0; m < 4; ++m)
#pragma unroll
        for (int r = 0; r < 4; ++r)
          C[(size_t)(rbase + m * 16 + r) * D_ + col] = (bf16_t)acc[m][n][r];
    }
  }
}

// ---------------------------------------------------------------------------
// Kernel 3: flash attention (r13/r15 version). Swapped-operand 32x32 MFMA,
// lane-local PV. grid (S/128, B*H), 4 waves x 32 q-rows, KVBLK=128 = two
// 64-key subtiles per barrier, NT=16. exp via v_exp_f32. K swap23 rows;
// 5-bit swizzle s(row)=(row&7)^((row>>3)&3) -> conflict-free b128 reads.
// ---------------------------------------------------------------------------
__global__ __launch_bounds__(256) void attn_kernel(
    const bf16_t* __restrict__ Q, const bf16_t* __restrict__ K,
    const bf16_t* __restrict__ Vt, bf16_t* __restrict__ O) {
  constexpr int NT = S_ / 128;
  constexpr float THR = 11.5416f;          // 8 * log2(e)
  __shared__ alignas(16) bf16_t Ks[2][2][64 * 64];
  __shared__ alignas(16) bf16_t Vs[2][2][64 * 64];
  const int t = threadIdx.x, lane = t & 63, wid = t >> 6;
  const int b = blockIdx.y >> 4, h = blockIdx.y & 15;
  const int qw = blockIdx.x * 128 + wid * 32;   // this wave's 32 q-rows
  const int q31 = lane & 31, hi = lane >> 5;

  // Q as B-operand frags: col=lane&31=q, k=hi*8+j = d within 16-slice.
  bf16x8 qb[4];
  {
    const size_t qrow = (size_t)(b * S_ + qw + q31) * D_ + h * HD_ + hi * 8;
#pragma unroll
    for (int ksl = 0; ksl < 4; ++ksl) {
      bf16x8 v = *(const bf16x8*)&Q[qrow + ksl * 16];
#pragma unroll
      for (int j = 0; j < 8; ++j)
        v[j] = (bf16_t)((float)v[j] * (0.125f * 1.44269504f));
      qb[ksl] = v;
    }
  }
  bf16x8 onesb;
#pragma unroll
  for (int j = 0; j < 8; ++j) onesb[j] = (bf16_t)1.0f;

  f32x16 ctx0 = {0.f,0.f,0.f,0.f,0.f,0.f,0.f,0.f,0.f,0.f,0.f,0.f,0.f,0.f,0.f,0.f};
  f32x16 ctx1 = ctx0, lf = ctx0;
  float mrow = -1e30f;

  // 5-bit swizzle: logical slot x at row r -> phys (x ^ (r&7) ^ ((r>>3)&3))*8.
  const int srow5 = (q31 & 7) ^ ((q31 >> 3) & 3);
  int sw[4];
#pragma unroll
  for (int x = 0; x < 4; ++x) sw[x] = ((x * 2 + hi) ^ srow5) * 8;

  // staging: wave w, chunk c covers LDS tile-rows c*32 + w*8 + (lane>>3);
  // phys slot (lane&7) holds logical slot (lane&7)^s(trow).
  // K global row = swap23(LDS row) (key permutation, algebra-neutral).
  const int trow = wid * 8 + (lane >> 3);
  const int krow_g = (trow & ~12) | ((trow & 4) << 1) | ((trow & 8) >> 1);
  const int st5 = (trow & 7) ^ ((trow >> 3) & 3);
  const int lslot = ((lane & 7) ^ st5) * 8;
  const bf16_t* Ksrc0 = K + (size_t)(b * S_ + krow_g) * D_ + h * HD_ + lslot;
  const bf16_t* Ksrc1 = K + (size_t)(b * S_ + 32 + krow_g) * D_ + h * HD_ + lslot;
  const bf16_t* Vsrc0 = Vt + (size_t)b * D_ * S_ + (size_t)(h * HD_ + trow) * S_ + lslot;
  const bf16_t* Vsrc1 = Vt + (size_t)b * D_ * S_ + (size_t)(h * HD_ + 32 + trow) * S_ + lslot;

  // prologue: stage tile-pair 0 (subtiles 0 and 1)
#pragma unroll
  for (int sb = 0; sb < 2; ++sb) {
    gload_lds16(Ksrc0 + (size_t)sb * 64 * D_, &Ks[0][sb][wid * 512]);
    gload_lds16(Ksrc1 + (size_t)sb * 64 * D_, &Ks[0][sb][2048 + wid * 512]);
    gload_lds16(Vsrc0 + sb * 64, &Vs[0][sb][wid * 512]);
    gload_lds16(Vsrc1 + sb * 64, &Vs[0][sb][2048 + wid * 512]);
  }

  // one 64-key subtile: QK^T + softmax + P-pack + l/PV accumulate
  auto SUB = [&](const bf16_t* Kb, const bf16_t* Vb) {
    f32x16 s0 = {0.f,0.f,0.f,0.f,0.f,0.f,0.f,0.f,0.f,0.f,0.f,0.f,0.f,0.f,0.f,0.f};
    f32x16 s1 = s0;
    __builtin_amdgcn_s_setprio(1);
#pragma unroll
    for (int ksl = 0; ksl < 4; ++ksl) {
      bf16x8 kb0 = *(const bf16x8*)&Kb[q31 * 64 + sw[ksl]];
      bf16x8 kb1 = *(const bf16x8*)&Kb[(32 + q31) * 64 + sw[ksl]];
      s0 = mfma32(kb0, qb[ksl], s0);
      s1 = mfma32(kb1, qb[ksl], s1);
    }
    __builtin_amdgcn_s_setprio(0);

    float mt = fmaxf(s0[0], s1[0]);
#pragma unroll
    for (int r = 1; r < 16; ++r) mt = fmaxf(fmaxf(mt, s0[r]), s1[r]);
    mt = fmaxf(mt, __shfl_xor(mt, 32));
    if (__any(mt > mrow + THR)) {
      float mnew = fmaxf(mrow, mt);
      float scl = fexp2(mrow - mnew);
      mrow = mnew;
#pragma unroll
      for (int r = 0; r < 16; ++r) {
        float sc = __shfl(scl, (r & 3) + 8 * (r >> 2) + 4 * hi);
        ctx0[r] *= sc; ctx1[r] *= sc; lf[r] *= sc;
      }
    }
#pragma unroll
    for (int r = 0; r < 16; ++r) {
      s0[r] = fexp2(s0[r] - mrow);
      s1[r] = fexp2(s1[r] - mrow);
    }

    bf16x8 pa[4];
#pragma unroll
    for (int ks = 0; ks < 4; ++ks) {
      union { u32 w[4]; bf16x8 v; } u;
      if (ks < 2) {
#pragma unroll
        for (int w = 0; w < 4; ++w)
          u.w[w] = pkbf(s0[(ks & 1) * 8 + 2 * w], s0[(ks & 1) * 8 + 2 * w + 1]);
      } else {
#pragma unroll
        for (int w = 0; w < 4; ++w)
          u.w[w] = pkbf(s1[(ks & 1) * 8 + 2 * w], s1[(ks & 1) * 8 + 2 * w + 1]);
      }
      pa[ks] = u.v;
    }

    __builtin_amdgcn_s_setprio(1);
#pragma unroll
    for (int ks = 0; ks < 4; ++ks) lf = mfma32(pa[ks], onesb, lf);
#pragma unroll
    for (int ks = 0; ks < 4; ++ks) {
      bf16x8 vb0 = *(const bf16x8*)&Vb[q31 * 64 + sw[ks]];
      bf16x8 vb1 = *(const bf16x8*)&Vb[(32 + q31) * 64 + sw[ks]];
      ctx0 = mfma32(pa[ks], vb0, ctx0);
      ctx1 = mfma32(pa[ks], vb1, ctx1);
    }
    __builtin_amdgcn_s_setprio(0);
  };

  for (int kt = 0; kt < NT; ++kt) {
    __syncthreads();                       // tile-pair kt resident
    const int cur = kt & 1, nxt = cur ^ 1;
    if (kt + 1 < NT) {
      const size_t ko = (size_t)(kt + 1) * 128 * D_;
      const size_t vo = (size_t)(kt + 1) * 128;
#pragma unroll
      for (int sb = 0; sb < 2; ++sb) {
        gload_lds16(Ksrc0 + ko + (size_t)sb * 64 * D_, &Ks[nxt][sb][wid * 512]);
        gload_lds16(Ksrc1 + ko + (size_t)sb * 64 * D_, &Ks[nxt][sb][2048 + wid * 512]);
        gload_lds16(Vsrc0 + vo + sb * 64, &Vs[nxt][sb][wid * 512]);
        gload_lds16(Vsrc1 + vo + sb * 64, &Vs[nxt][sb][2048 + wid * 512]);
      }
    }
    SUB(&Ks[cur][0][0], &Vs[cur][0][0]);
    SUB(&Ks[cur][1][0], &Vs[cur][1][0]);
  }

  // epilogue: ctx D-frag row = q = crow(reg,hi), col = d = dchunk*32+(lane&31)
#pragma unroll
  for (int r = 0; r < 16; ++r) {
    const int q = (r & 3) + 8 * (r >> 2) + 4 * hi;
    const float inv = 1.f / lf[r];
    const size_t ro = (size_t)(b * S_ + qw + q) * D_ + h * HD_ + q31;
    O[ro]      = (bf16_t)(ctx0[r] * inv);
    O[ro + 32] = (bf16_t)(ctx1[r] * inv);
  }
}

// ---------------------------------------------------------------------------
// Kernel 4: out = LayerNorm(a + res) * g + b.  a,res bf16; g,b f32.
// ---------------------------------------------------------------------------
template <typename OUT>
__global__ __launch_bounds__(256) void add_ln_kernel(
    const bf16_t* __restrict__ a, const bf16_t* __restrict__ res,
    const float* __restrict__ g, const float* __restrict__ be,
    OUT* __restrict__ out) {
  const int t = threadIdx.x;
  const int d0 = t * 4;
  const size_t base = (size_t)blockIdx.x * D_ + d0;
  bf16x4v av = *(const bf16x4v*)&a[base];
  bf16x4v rv = *(const bf16x4v*)&res[base];
  float x[4];
  float s1 = 0.f, s2 = 0.f;
#pragma unroll
  for (int e = 0; e < 4; ++e) {
    x[e] = (float)av[e] + (float)rv[e];
    s1 += x[e];
    s2 += x[e] * x[e];
  }
#pragma unroll
  for (int o = 32; o > 0; o >>= 1) {
    s1 += __shfl_down(s1, o);
    s2 += __shfl_down(s2, o);
  }
  __shared__ float red[8];
  const int lane = t & 63, wid = t >> 6;
  if (lane == 0) { red[wid] = s1; red[4 + wid] = s2; }
  __syncthreads();
  if (t == 0) {
    float t1 = red[0] + red[1] + red[2] + red[3];
    float t2 = red[4] + red[5] + red[6] + red[7];
    float mu = t1 * (1.f / D_);
    float var = t2 * (1.f / D_) - mu * mu;
    red[0] = mu;
    red[1] = rsqrtf(var + 1e-5f);
  }
  __syncthreads();
  const float mu = red[0], rstd = red[1];
  const float4 gv = *(const float4*)&g[d0];
  const float4 bv = *(const float4*)&be[d0];
  float y[4];
  y[0] = (x[0] - mu) * rstd * gv.x + bv.x;
  y[1] = (x[1] - mu) * rstd * gv.y + bv.y;
  y[2] = (x[2] - mu) * rstd * gv.z + bv.z;
  y[3] = (x[3] - mu) * rstd * gv.w + bv.w;
  if constexpr (sizeof(OUT) == 2) {
    bf16x4v o;
    o[0] = (bf16_t)y[0]; o[1] = (bf16_t)y[1]; o[2] = (bf16_t)y[2]; o[3] = (bf16_t)y[3];
    *(bf16x4v*)&out[base] = o;
  } else {
    float4 o = {y[0], y[1], y[2], y[3]};
    *(float4*)&out[base] = o;
  }
}

// ---------------------------------------------------------------------------
extern "C" void kernel_launch(void* const* d_in, const int* in_sizes, int n_in,
                              void* d_out, int out_size, void* d_ws, size_t ws_size,
                              hipStream_t stream) {
  const float* key   = (const float*)d_in[0];
  const float* value = (const float*)d_in[1];
  const float* query = (const float*)d_in[2];
  const float* Wq = (const float*)d_in[3];
  const float* Wk = (const float*)d_in[4];
  const float* Wv = (const float*)d_in[5];
  const float* Wo = (const float*)d_in[6];
  const float* W1 = (const float*)d_in[7];
  const float* b1 = (const float*)d_in[8];
  const float* W2 = (const float*)d_in[9];
  const float* b2 = (const float*)d_in[10];
  const float* g1 = (const float*)d_in[11];
  const float* be1 = (const float*)d_in[12];
  const float* g2 = (const float*)d_in[13];
  const float* be2 = (const float*)d_in[14];
  float* out = (float*)d_out;

  bf16_t* ws = (bf16_t*)d_ws;
  const size_t NB = (size_t)B_ * S_ * D_;  // 4 Mi elems
  bf16_t* qpe = ws + 0 * NB;
  bf16_t* kpe = ws + 1 * NB;
  bf16_t* vpe = ws + 2 * NB;
  bf16_t* Qp  = ws + 3 * NB;
  bf16_t* Kp  = ws + 4 * NB;
  bf16_t* Vt  = ws + 5 * NB;   // [B][D][S] transposed V projection
  bf16_t* ctx = kpe;  // dead after QKV gemm
  bf16_t* ao  = vpe;  // dead after QKV gemm
  bf16_t* x1  = Qp;   // dead after attention
  bf16_t* hh  = Kp;   // dead after attention
  bf16_t* ff  = Vt;   // dead after attention

  // bf16 weights live in d_out (16 MB; 6 x 2 MB used, overwritten by final LN)
  bf16_t* wb = (bf16_t*)d_out;
  const size_t WN = (size_t)D_ * D_;
  bf16_t* Wqb = wb + 0 * WN;
  bf16_t* Wkb = wb + 1 * WN;
  bf16_t* Wvb = wb + 2 * WN;
  bf16_t* Wob = wb + 3 * WN;
  bf16_t* W1b = wb + 4 * WN;
  bf16_t* W2b = wb + 5 * WN;

  dim3 sgrid(16, 32);                          // 512 blocks (swizzled in-kernel)

  cvtw_kernel<<<dim3(D_ * D_ / 1024, 6), 256, 0, stream>>>(
      Wq, Wk, Wv, Wo, W1, W2, wb);
  addpe_kernel<<<B_ * S_, 256, 0, stream>>>(query, key, value, qpe, kpe, vpe);

  gemm_qkv<<<dim3(8, 32, 3), 256, 0, stream>>>(
      qpe, kpe, vpe, Wqb, Wkb, Wvb, Qp, Kp, Vt);

  attn_kernel<<<dim3(S_ / 128, B_ * H_), 256, 0, stream>>>(Qp, Kp, Vt, ctx);

  gemm_s<0><<<sgrid, 256, 0, stream>>>(ctx, Wob, nullptr, ao);
  add_ln_kernel<bf16_t><<<B_ * S_, 256, 0, stream>>>(ao, qpe, g1, be1, x1);

  gemm_s<2><<<sgrid, 256, 0, stream>>>(x1, W1b, b1, hh);
  gemm_s<1><<<sgrid, 256, 0, stream>>>(hh, W2b, b2, ff);
  add_ln_kernel<float><<<B_ * S_, 256, 0, stream>>>(ff, x1, g2, be2, out);
}

// Round 17
// 189.007 us; speedup vs baseline: 1.1738x; 1.0079x over previous
//
#include <hip/hip_runtime.h>
#include <hip/hip_bf16.h>
#include <math.h>

// ---------------------------------------------------------------------------
// TransformerLayer: B=2 S=2048 D=1024 H=16 HD=64. I/O f32, internals bf16.
// Round 17: r16 + cvtw/addpe merged into one prep_kernel launch (independent
// work, was serialized across two dispatches). Everything else identical to
// r16 (190.5 us).
// ---------------------------------------------------------------------------

#define B_ 2
#define S_ 2048
#define D_ 1024
#define H_ 16
#define HD_ 64

typedef __bf16 bf16_t;
typedef __bf16 bf16x8 __attribute__((ext_vector_type(8)));
typedef __bf16 bf16x4v __attribute__((ext_vector_type(4)));
typedef float f32x4 __attribute__((ext_vector_type(4)));
typedef float f32x16 __attribute__((ext_vector_type(16)));
typedef unsigned int u32;

__device__ __forceinline__ f32x4 mfma16(bf16x8 a, bf16x8 b, f32x4 c) {
  return __builtin_amdgcn_mfma_f32_16x16x32_bf16(a, b, c, 0, 0, 0);
}
__device__ __forceinline__ f32x16 mfma32(bf16x8 a, bf16x8 b, f32x16 c) {
  return __builtin_amdgcn_mfma_f32_32x32x16_bf16(a, b, c, 0, 0, 0);
}
__device__ __forceinline__ u32 pkbf(float a, float b) {
  union { bf16_t h[2]; u32 u; } t;
  t.h[0] = (bf16_t)a; t.h[1] = (bf16_t)b;
  return t.u;
}
__device__ __forceinline__ float fexp2(float x) {       // single v_exp_f32
  return __builtin_amdgcn_exp2f(x);
}

// global -> LDS direct copy, 16B/lane. LDS dest: wave-uniform base + lane*16.
__device__ __forceinline__ void gload_lds16(const bf16_t* g, bf16_t* l) {
  __builtin_amdgcn_global_load_lds((const __attribute__((address_space(1))) void*)g,
                                   (__attribute__((address_space(3))) void*)l,
                                   16, 0, 0);
}

// ---------------------------------------------------------------------------
// Kernel 1: fused prep. bid < B*S: positional-encoding+add row (f32->bf16,
// q/k/v one pass). bid >= B*S: weight f32->bf16 convert chunk (6 matrices).
// ---------------------------------------------------------------------------
__global__ __launch_bounds__(256) void prep_kernel(
    const float* __restrict__ q, const float* __restrict__ k,
    const float* __restrict__ v,
    bf16_t* __restrict__ qo, bf16_t* __restrict__ ko, bf16_t* __restrict__ vo,
    const float* __restrict__ w0, const float* __restrict__ w1,
    const float* __restrict__ w2, const float* __restrict__ w3,
    const float* __restrict__ w4, const float* __restrict__ w5,
    bf16_t* __restrict__ wdst) {
  const int bid = blockIdx.x;
  if (bid < B_ * S_) {
    const int row = bid;                 // b*S + s
    const int s = row & (S_ - 1);
    const int d0 = threadIdx.x * 4;
    const size_t base = (size_t)row * D_ + d0;
    float pe[4];
#pragma unroll
    for (int p = 0; p < 2; ++p) {
      float div = __expf((float)(d0 + 2 * p) * -0.008994473019508f);
      float rev = (float)s * div * 0.15915494309189535f;   // ang / (2*pi)
      float rf = rev - floorf(rev);
      pe[2 * p]     = __builtin_amdgcn_sinf(rf);
      pe[2 * p + 1] = __builtin_amdgcn_cosf(rf);
    }
    float4 qv = *(const float4*)&q[base];
    float4 kv = *(const float4*)&k[base];
    float4 vv = *(const float4*)&v[base];
    bf16x4v qr, kr, vr;
    qr[0] = (bf16_t)(qv.x + pe[0]); qr[1] = (bf16_t)(qv.y + pe[1]);
    qr[2] = (bf16_t)(qv.z + pe[2]); qr[3] = (bf16_t)(qv.w + pe[3]);
    kr[0] = (bf16_t)(kv.x + pe[0]); kr[1] = (bf16_t)(kv.y + pe[1]);
    kr[2] = (bf16_t)(kv.z + pe[2]); kr[3] = (bf16_t)(kv.w + pe[3]);
    vr[0] = (bf16_t)(vv.x + pe[0]); vr[1] = (bf16_t)(vv.y + pe[1]);
    vr[2] = (bf16_t)(vv.z + pe[2]); vr[3] = (bf16_t)(vv.w + pe[3]);
    *(bf16x4v*)&qo[base] = qr;
    *(bf16x4v*)&ko[base] = kr;
    *(bf16x4v*)&vo[base] = vr;
  } else {
    const int idx = bid - B_ * S_;       // 0 .. 6*1024-1
    const int wsel = idx >> 10;
    const float* src = wsel == 0 ? w0 : wsel == 1 ? w1 : wsel == 2 ? w2
                     : wsel == 3 ? w3 : wsel == 4 ? w4 : w5;
    const size_t off = (size_t)(idx & 1023) * 1024 + threadIdx.x * 4;
    float4 vv = *(const float4*)(src + off);
    bf16x4v r;
    r[0] = (bf16_t)vv.x; r[1] = (bf16_t)vv.y; r[2] = (bf16_t)vv.z; r[3] = (bf16_t)vv.w;
    *(bf16x4v*)(wdst + (size_t)wsel * (D_ * D_) + off) = r;
  }
}

// ---------------------------------------------------------------------------
// Kernel 2a: singles NT GEMM, tile 128x64 (512 blocks, XCD-chunk swizzled),
// BK=64 = two 32-chunks per barrier (16 barriers), 4 waves (2x2, each 64x32),
// 2-phase dbuf of chunk-pairs, all-gload_lds.
// EPI: 0 plain, 1 +bias, 2 +bias+relu
// ---------------------------------------------------------------------------
template <int EPI>
__global__ __launch_bounds__(256) void gemm_s(
    const bf16_t* __restrict__ A, const bf16_t* __restrict__ Wb,
    const float* __restrict__ bias, bf16_t* __restrict__ C) {
  constexpr int Kd = 1024, NT2 = Kd / 64;
  __shared__ alignas(16) bf16_t As[2][2][128 * 32];   // [buf][chunk]
  __shared__ alignas(16) bf16_t Bs[2][2][64 * 32];
  const int t = threadIdx.x, lane = t & 63, wid = t >> 6;
  // XCD-chunk swizzle (m204, nwg%8==0): 512 blocks = 8 XCDs x 64.
  const int bid = blockIdx.y * 16 + blockIdx.x;
  const int virt = (bid & 7) * 64 + (bid >> 3);
  const int m0 = (virt >> 4) * 128, n0 = (virt & 15) * 64;

  const bf16_t* Asrc0 = A + (size_t)(m0 + wid * 16 + (lane >> 2)) * Kd + (lane & 3) * 8;
  const bf16_t* Asrc1 = Asrc0 + (size_t)64 * Kd;
  const bf16_t* Wsrc = Wb + (size_t)(n0 + wid * 16 + (lane >> 2)) * Kd + (lane & 3) * 8;

  const f32x4 zero = {0.f, 0.f, 0.f, 0.f};
  f32x4 acc[4][2];
#pragma unroll
  for (int m = 0; m < 4; ++m) { acc[m][0] = zero; acc[m][1] = zero; }

#pragma unroll
  for (int c = 0; c < 2; ++c) {
    gload_lds16(Asrc0 + c * 32, &As[0][c][wid * 512]);
    gload_lds16(Asrc1 + c * 32, &As[0][c][2048 + wid * 512]);
    gload_lds16(Wsrc + c * 32,  &Bs[0][c][wid * 512]);
  }

  const int wr = wid >> 1, wc = wid & 1;
#pragma unroll 2
  for (int kt = 0; kt < NT2; ++kt) {
    __syncthreads();                       // chunk-pair kt resident
    const int cur = kt & 1, nxt = cur ^ 1;
    if (kt + 1 < NT2) {
      const int k0 = (kt + 1) * 64;
#pragma unroll
      for (int c = 0; c < 2; ++c) {
        gload_lds16(Asrc0 + k0 + c * 32, &As[nxt][c][wid * 512]);
        gload_lds16(Asrc1 + k0 + c * 32, &As[nxt][c][2048 + wid * 512]);
        gload_lds16(Wsrc + k0 + c * 32,  &Bs[nxt][c][wid * 512]);
      }
    }
#pragma unroll
    for (int c = 0; c < 2; ++c) {
      bf16x8 af[4], bfr[2];
#pragma unroll
      for (int m = 0; m < 4; ++m)
        af[m] = *(const bf16x8*)&As[cur][c][(wr * 64 + m * 16 + (lane & 15)) * 32 + (lane >> 4) * 8];
#pragma unroll
      for (int n = 0; n < 2; ++n)
        bfr[n] = *(const bf16x8*)&Bs[cur][c][(wc * 32 + n * 16 + (lane & 15)) * 32 + (lane >> 4) * 8];
      __builtin_amdgcn_s_setprio(1);
#pragma unroll
      for (int m = 0; m < 4; ++m)
#pragma unroll
        for (int n = 0; n < 2; ++n)
          acc[m][n] = mfma16(af[m], bfr[n], acc[m][n]);
      __builtin_amdgcn_s_setprio(0);
    }
  }

  const int rbase = m0 + wr * 64 + (lane >> 4) * 4;
  const int cbase = n0 + wc * 32 + (lane & 15);
#pragma unroll
  for (int n = 0; n < 2; ++n) {
    const int col = cbase + n * 16;
    float bv = (EPI >= 1) ? bias[col] : 0.f;
#pragma unroll
    for (int m = 0; m < 4; ++m)
#pragma unroll
      for (int r = 0; r < 4; ++r) {
        float vv = acc[m][n][r] + bv;
        if (EPI == 2) vv = fmaxf(vv, 0.f);
        C[(size_t)(rbase + m * 16 + r) * D_ + col] = (bf16_t)vv;
      }
  }
}

// ---------------------------------------------------------------------------
// Kernel 2b: QKV batched GEMM, tile 128x128 (768 blocks, XCD-chunk swizzled),
// BK=32, 4 waves (2x2, each 64x64), 2-phase dbuf. r9-proven staging/K-loop.
// virt z: 0=Q, 1=K (direct stores); 2=V^T via LDS transpose bounce reusing
// the named As (d<64) / Bs (d>=64) arrays -> coalesced bf16x8 stores along s.
// ---------------------------------------------------------------------------
__global__ __launch_bounds__(256) void gemm_qkv(
    const bf16_t* __restrict__ a0p, const bf16_t* __restrict__ a1p,
    const bf16_t* __restrict__ a2p,
    const bf16_t* __restrict__ w0p, const bf16_t* __restrict__ w1p,
    const bf16_t* __restrict__ w2p,
    bf16_t* __restrict__ o0, bf16_t* __restrict__ o1, bf16_t* __restrict__ o2) {
  constexpr int Kd = 1024, NT = Kd / 32;
  __shared__ alignas(16) bf16_t As[2][128 * 32];
  __shared__ alignas(16) bf16_t Bs[2][128 * 32];
  const int t = threadIdx.x, lane = t & 63, wid = t >> 6;
  const int g = lane >> 4, c16 = lane & 15;
  // XCD-chunk swizzle (m204, nwg%8==0): 768 blocks = 8 XCDs x 96.
  const int bid = blockIdx.z * 256 + blockIdx.y * 8 + blockIdx.x;
  const int virt = (bid & 7) * 96 + (bid >> 3);
  const int zz = virt >> 8;
  const int m0 = ((virt >> 3) & 31) * 128, n0 = (virt & 7) * 128;

  const bf16_t* A = a0p;
  const bf16_t* Wb = w0p;
  if (zz == 1) { A = a1p; Wb = w1p; }
  else if (zz == 2) { A = a2p; Wb = w2p; }

  const bf16_t* Asrc0 = A + (size_t)(m0 + wid * 16 + (lane >> 2)) * Kd + (lane & 3) * 8;
  const bf16_t* Asrc1 = Asrc0 + (size_t)64 * Kd;
  const bf16_t* Wsrc0 = Wb + (size_t)(n0 + wid * 16 + (lane >> 2)) * Kd + (lane & 3) * 8;
  const bf16_t* Wsrc1 = Wsrc0 + (size_t)64 * Kd;

  const f32x4 zero = {0.f, 0.f, 0.f, 0.f};
  f32x4 acc[4][4];
#pragma unroll
  for (int m = 0; m < 4; ++m)
#pragma unroll
    for (int n = 0; n < 4; ++n) acc[m][n] = zero;

  gload_lds16(Asrc0, &As[0][wid * 512]);
  gload_lds16(Asrc1, &As[0][2048 + wid * 512]);
  gload_lds16(Wsrc0, &Bs[0][wid * 512]);
  gload_lds16(Wsrc1, &Bs[0][2048 + wid * 512]);

  const int wr = wid >> 1, wc = wid & 1;
#pragma unroll 2
  for (int kt = 0; kt < NT; ++kt) {
    __syncthreads();
    const int cur = kt & 1, nxt = cur ^ 1;
    if (kt + 1 < NT) {
      const int k0 = (kt + 1) * 32;
      gload_lds16(Asrc0 + k0, &As[nxt][wid * 512]);
      gload_lds16(Asrc1 + k0, &As[nxt][2048 + wid * 512]);
      gload_lds16(Wsrc0 + k0, &Bs[nxt][wid * 512]);
      gload_lds16(Wsrc1 + k0, &Bs[nxt][2048 + wid * 512]);
    }
    bf16x8 af[4], bfr[4];
#pragma unroll
    for (int m = 0; m < 4; ++m)
      af[m] = *(const bf16x8*)&As[cur][(wr * 64 + m * 16 + c16) * 32 + g * 8];
#pragma unroll
    for (int n = 0; n < 4; ++n)
      bfr[n] = *(const bf16x8*)&Bs[cur][(wc * 64 + n * 16 + c16) * 32 + g * 8];
    __builtin_amdgcn_s_setprio(1);
#pragma unroll
    for (int m = 0; m < 4; ++m)
#pragma unroll
      for (int n = 0; n < 4; ++n)
        acc[m][n] = mfma16(af[m], bfr[n], acc[m][n]);
    __builtin_amdgcn_s_setprio(0);
  }

  const int rbase = m0 + wr * 64 + g * 4;
  const int cbase = n0 + wc * 64 + c16;
  if (zz == 2) {
    // V^T transpose bounce. Tile is 128 d-cols x 128 s-rows; store s-major
    // [d_l][s_l] with bank swizzle s_l ^= (d_l&7)<<4. d_l<64 -> As, else Bs
    // (wave-uniform: wc). All waves' last LDS reads completed first.
    __syncthreads();
#pragma unroll
    for (int n = 0; n < 4; ++n) {
      const int d_l = wc * 64 + n * 16 + c16;   // 0..127
      const int dl6 = n * 16 + c16;             // d_l & 63
      const int sxh = (d_l & 7) << 4;
      bf16_t* const half = wc ? &Bs[0][0] : &As[0][0];
#pragma unroll
      for (int m = 0; m < 4; ++m) {
        const int s_l = (wr * 64 + g * 4 + m * 16) ^ sxh;   // 4-aligned
        u32* p = (u32*)&half[dl6 * 128 + s_l];
        p[0] = pkbf(acc[m][n][0], acc[m][n][1]);
        p[1] = pkbf(acc[m][n][2], acc[m][n][3]);
      }
    }
    __syncthreads();
    const int bb = m0 >> 11;
    const int sbase = m0 & (S_ - 1);
    const size_t obase = (size_t)bb * D_ * S_ + sbase;
#pragma unroll
    for (int p = 0; p < 8; ++p) {
      const int d_l = p * 16 + (t >> 4);        // 0..127
      const bf16_t* const hr = (p < 4) ? &As[0][0] : &Bs[0][0];
      const int dl6 = d_l & 63;
      const int s0i = (t & 15) * 8;
      const int sx = s0i ^ ((d_l & 7) << 4);
      bf16x8 v = *(const bf16x8*)&hr[dl6 * 128 + sx];
      *(bf16x8*)&o2[obase + (size_t)(n0 + d_l) * S_ + s0i] = v;
    }
  } else {
    bf16_t* C = (zz == 1) ? o1 : o0;
#pragma unroll
    for (int n = 0; n < 4; ++n) {
      const int col = cbase + n * 16;
#pragma unroll
      for (int m = 0; m < 4; ++m)
#pragma unroll
        for (int r = 0; r < 4; ++r)
          C[(size_t)(rbase + m * 16 + r) * D_ + col] = (bf16_t)acc[m][n][r];
    }
  }
}

// ---------------------------------------------------------------------------
// Kernel 3: flash attention (r13/r15 version). Swapped-operand 32x32 MFMA,
// lane-local PV. grid (S/128, B*H), 4 waves x 32 q-rows, KVBLK=128 = two
// 64-key subtiles per barrier, NT=16. exp via v_exp_f32. K swap23 rows;
// 5-bit swizzle s(row)=(row&7)^((row>>3)&3) -> conflict-free b128 reads.
// ---------------------------------------------------------------------------
__global__ __launch_bounds__(256) void attn_kernel(
    const bf16_t* __restrict__ Q, const bf16_t* __restrict__ K,
    const bf16_t* __restrict__ Vt, bf16_t* __restrict__ O) {
  constexpr int NT = S_ / 128;
  constexpr float THR = 11.5416f;          // 8 * log2(e)
  __shared__ alignas(16) bf16_t Ks[2][2][64 * 64];
  __shared__ alignas(16) bf16_t Vs[2][2][64 * 64];
  const int t = threadIdx.x, lane = t & 63, wid = t >> 6;
  const int b = blockIdx.y >> 4, h = blockIdx.y & 15;
  const int qw = blockIdx.x * 128 + wid * 32;   // this wave's 32 q-rows
  const int q31 = lane & 31, hi = lane >> 5;

  // Q as B-operand frags: col=lane&31=q, k=hi*8+j = d within 16-slice.
  bf16x8 qb[4];
  {
    const size_t qrow = (size_t)(b * S_ + qw + q31) * D_ + h * HD_ + hi * 8;
#pragma unroll
    for (int ksl = 0; ksl < 4; ++ksl) {
      bf16x8 v = *(const bf16x8*)&Q[qrow + ksl * 16];
#pragma unroll
      for (int j = 0; j < 8; ++j)
        v[j] = (bf16_t)((float)v[j] * (0.125f * 1.44269504f));
      qb[ksl] = v;
    }
  }
  bf16x8 onesb;
#pragma unroll
  for (int j = 0; j < 8; ++j) onesb[j] = (bf16_t)1.0f;

  f32x16 ctx0 = {0.f,0.f,0.f,0.f,0.f,0.f,0.f,0.f,0.f,0.f,0.f,0.f,0.f,0.f,0.f,0.f};
  f32x16 ctx1 = ctx0, lf = ctx0;
  float mrow = -1e30f;

  // 5-bit swizzle: logical slot x at row r -> phys (x ^ (r&7) ^ ((r>>3)&3))*8.
  const int srow5 = (q31 & 7) ^ ((q31 >> 3) & 3);
  int sw[4];
#pragma unroll
  for (int x = 0; x < 4; ++x) sw[x] = ((x * 2 + hi) ^ srow5) * 8;

  // staging: wave w, chunk c covers LDS tile-rows c*32 + w*8 + (lane>>3);
  // phys slot (lane&7) holds logical slot (lane&7)^s(trow).
  // K global row = swap23(LDS row) (key permutation, algebra-neutral).
  const int trow = wid * 8 + (lane >> 3);
  const int krow_g = (trow & ~12) | ((trow & 4) << 1) | ((trow & 8) >> 1);
  const int st5 = (trow & 7) ^ ((trow >> 3) & 3);
  const int lslot = ((lane & 7) ^ st5) * 8;
  const bf16_t* Ksrc0 = K + (size_t)(b * S_ + krow_g) * D_ + h * HD_ + lslot;
  const bf16_t* Ksrc1 = K + (size_t)(b * S_ + 32 + krow_g) * D_ + h * HD_ + lslot;
  const bf16_t* Vsrc0 = Vt + (size_t)b * D_ * S_ + (size_t)(h * HD_ + trow) * S_ + lslot;
  const bf16_t* Vsrc1 = Vt + (size_t)b * D_ * S_ + (size_t)(h * HD_ + 32 + trow) * S_ + lslot;

  // prologue: stage tile-pair 0 (subtiles 0 and 1)
#pragma unroll
  for (int sb = 0; sb < 2; ++sb) {
    gload_lds16(Ksrc0 + (size_t)sb * 64 * D_, &Ks[0][sb][wid * 512]);
    gload_lds16(Ksrc1 + (size_t)sb * 64 * D_, &Ks[0][sb][2048 + wid * 512]);
    gload_lds16(Vsrc0 + sb * 64, &Vs[0][sb][wid * 512]);
    gload_lds16(Vsrc1 + sb * 64, &Vs[0][sb][2048 + wid * 512]);
  }

  // one 64-key subtile: QK^T + softmax + P-pack + l/PV accumulate
  auto SUB = [&](const bf16_t* Kb, const bf16_t* Vb) {
    f32x16 s0 = {0.f,0.f,0.f,0.f,0.f,0.f,0.f,0.f,0.f,0.f,0.f,0.f,0.f,0.f,0.f,0.f};
    f32x16 s1 = s0;
    __builtin_amdgcn_s_setprio(1);
#pragma unroll
    for (int ksl = 0; ksl < 4; ++ksl) {
      bf16x8 kb0 = *(const bf16x8*)&Kb[q31 * 64 + sw[ksl]];
      bf16x8 kb1 = *(const bf16x8*)&Kb[(32 + q31) * 64 + sw[ksl]];
      s0 = mfma32(kb0, qb[ksl], s0);
      s1 = mfma32(kb1, qb[ksl], s1);
    }
    __builtin_amdgcn_s_setprio(0);

    float mt = fmaxf(s0[0], s1[0]);
#pragma unroll
    for (int r = 1; r < 16; ++r) mt = fmaxf(fmaxf(mt, s0[r]), s1[r]);
    mt = fmaxf(mt, __shfl_xor(mt, 32));
    if (__any(mt > mrow + THR)) {
      float mnew = fmaxf(mrow, mt);
      float scl = fexp2(mrow - mnew);
      mrow = mnew;
#pragma unroll
      for (int r = 0; r < 16; ++r) {
        float sc = __shfl(scl, (r & 3) + 8 * (r >> 2) + 4 * hi);
        ctx0[r] *= sc; ctx1[r] *= sc; lf[r] *= sc;
      }
    }
#pragma unroll
    for (int r = 0; r < 16; ++r) {
      s0[r] = fexp2(s0[r] - mrow);
      s1[r] = fexp2(s1[r] - mrow);
    }

    bf16x8 pa[4];
#pragma unroll
    for (int ks = 0; ks < 4; ++ks) {
      union { u32 w[4]; bf16x8 v; } u;
      if (ks < 2) {
#pragma unroll
        for (int w = 0; w < 4; ++w)
          u.w[w] = pkbf(s0[(ks & 1) * 8 + 2 * w], s0[(ks & 1) * 8 + 2 * w + 1]);
      } else {
#pragma unroll
        for (int w = 0; w < 4; ++w)
          u.w[w] = pkbf(s1[(ks & 1) * 8 + 2 * w], s1[(ks & 1) * 8 + 2 * w + 1]);
      }
      pa[ks] = u.v;
    }

    __builtin_amdgcn_s_setprio(1);
#pragma unroll
    for (int ks = 0; ks < 4; ++ks) lf = mfma32(pa[ks], onesb, lf);
#pragma unroll
    for (int ks = 0; ks < 4; ++ks) {
      bf16x8 vb0 = *(const bf16x8*)&Vb[q31 * 64 + sw[ks]];
      bf16x8 vb1 = *(const bf16x8*)&Vb[(32 + q31) * 64 + sw[ks]];
      ctx0 = mfma32(pa[ks], vb0, ctx0);
      ctx1 = mfma32(pa[ks], vb1, ctx1);
    }
    __builtin_amdgcn_s_setprio(0);
  };

  for (int kt = 0; kt < NT; ++kt) {
    __syncthreads();                       // tile-pair kt resident
    const int cur = kt & 1, nxt = cur ^ 1;
    if (kt + 1 < NT) {
      const size_t ko = (size_t)(kt + 1) * 128 * D_;
      const size_t vo = (size_t)(kt + 1) * 128;
#pragma unroll
      for (int sb = 0; sb < 2; ++sb) {
        gload_lds16(Ksrc0 + ko + (size_t)sb * 64 * D_, &Ks[nxt][sb][wid * 512]);
        gload_lds16(Ksrc1 + ko + (size_t)sb * 64 * D_, &Ks[nxt][sb][2048 + wid * 512]);
        gload_lds16(Vsrc0 + vo + sb * 64, &Vs[nxt][sb][wid * 512]);
        gload_lds16(Vsrc1 + vo + sb * 64, &Vs[nxt][sb][2048 + wid * 512]);
      }
    }
    SUB(&Ks[cur][0][0], &Vs[cur][0][0]);
    SUB(&Ks[cur][1][0], &Vs[cur][1][0]);
  }

  // epilogue: ctx D-frag row = q = crow(reg,hi), col = d = dchunk*32+(lane&31)
#pragma unroll
  for (int r = 0; r < 16; ++r) {
    const int q = (r & 3) + 8 * (r >> 2) + 4 * hi;
    const float inv = 1.f / lf[r];
    const size_t ro = (size_t)(b * S_ + qw + q) * D_ + h * HD_ + q31;
    O[ro]      = (bf16_t)(ctx0[r] * inv);
    O[ro + 32] = (bf16_t)(ctx1[r] * inv);
  }
}

// ---------------------------------------------------------------------------
// Kernel 4: out = LayerNorm(a + res) * g + b.  a,res bf16; g,b f32.
// ---------------------------------------------------------------------------
template <typename OUT>
__global__ __launch_bounds__(256) void add_ln_kernel(
    const bf16_t* __restrict__ a, const bf16_t* __restrict__ res,
    const float* __restrict__ g, const float* __restrict__ be,
    OUT* __restrict__ out) {
  const int t = threadIdx.x;
  const int d0 = t * 4;
  const size_t base = (size_t)blockIdx.x * D_ + d0;
  bf16x4v av = *(const bf16x4v*)&a[base];
  bf16x4v rv = *(const bf16x4v*)&res[base];
  float x[4];
  float s1 = 0.f, s2 = 0.f;
#pragma unroll
  for (int e = 0; e < 4; ++e) {
    x[e] = (float)av[e] + (float)rv[e];
    s1 += x[e];
    s2 += x[e] * x[e];
  }
#pragma unroll
  for (int o = 32; o > 0; o >>= 1) {
    s1 += __shfl_down(s1, o);
    s2 += __shfl_down(s2, o);
  }
  __shared__ float red[8];
  const int lane = t & 63, wid = t >> 6;
  if (lane == 0) { red[wid] = s1; red[4 + wid] = s2; }
  __syncthreads();
  if (t == 0) {
    float t1 = red[0] + red[1] + red[2] + red[3];
    float t2 = red[4] + red[5] + red[6] + red[7];
    float mu = t1 * (1.f / D_);
    float var = t2 * (1.f / D_) - mu * mu;
    red[0] = mu;
    red[1] = rsqrtf(var + 1e-5f);
  }
  __syncthreads();
  const float mu = red[0], rstd = red[1];
  const float4 gv = *(const float4*)&g[d0];
  const float4 bv = *(const float4*)&be[d0];
  float y[4];
  y[0] = (x[0] - mu) * rstd * gv.x + bv.x;
  y[1] = (x[1] - mu) * rstd * gv.y + bv.y;
  y[2] = (x[2] - mu) * rstd * gv.z + bv.z;
  y[3] = (x[3] - mu) * rstd * gv.w + bv.w;
  if constexpr (sizeof(OUT) == 2) {
    bf16x4v o;
    o[0] = (bf16_t)y[0]; o[1] = (bf16_t)y[1]; o[2] = (bf16_t)y[2]; o[3] = (bf16_t)y[3];
    *(bf16x4v*)&out[base] = o;
  } else {
    float4 o = {y[0], y[1], y[2], y[3]};
    *(float4*)&out[base] = o;
  }
}

// ---------------------------------------------------------------------------
extern "C" void kernel_launch(void* const* d_in, const int* in_sizes, int n_in,
                              void* d_out, int out_size, void* d_ws, size_t ws_size,
                              hipStream_t stream) {
  const float* key   = (const float*)d_in[0];
  const float* value = (const float*)d_in[1];
  const float* query = (const float*)d_in[2];
  const float* Wq = (const float*)d_in[3];
  const float* Wk = (const float*)d_in[4];
  const float* Wv = (const float*)d_in[5];
  const float* Wo = (const float*)d_in[6];
  const float* W1 = (const float*)d_in[7];
  const float* b1 = (const float*)d_in[8];
  const float* W2 = (const float*)d_in[9];
  const float* b2 = (const float*)d_in[10];
  const float* g1 = (const float*)d_in[11];
  const float* be1 = (const float*)d_in[12];
  const float* g2 = (const float*)d_in[13];
  const float* be2 = (const float*)d_in[14];
  float* out = (float*)d_out;

  bf16_t* ws = (bf16_t*)d_ws;
  const size_t NB = (size_t)B_ * S_ * D_;  // 4 Mi elems
  bf16_t* qpe = ws + 0 * NB;
  bf16_t* kpe = ws + 1 * NB;
  bf16_t* vpe = ws + 2 * NB;
  bf16_t* Qp  = ws + 3 * NB;
  bf16_t* Kp  = ws + 4 * NB;
  bf16_t* Vt  = ws + 5 * NB;   // [B][D][S] transposed V projection
  bf16_t* ctx = kpe;  // dead after QKV gemm
  bf16_t* ao  = vpe;  // dead after QKV gemm
  bf16_t* x1  = Qp;   // dead after attention
  bf16_t* hh  = Kp;   // dead after attention
  bf16_t* ff  = Vt;   // dead after attention

  // bf16 weights live in d_out (16 MB; 6 x 2 MB used, overwritten by final LN)
  bf16_t* wb = (bf16_t*)d_out;
  const size_t WN = (size_t)D_ * D_;
  bf16_t* Wqb = wb + 0 * WN;
  bf16_t* Wkb = wb + 1 * WN;
  bf16_t* Wvb = wb + 2 * WN;
  bf16_t* Wob = wb + 3 * WN;
  bf16_t* W1b = wb + 4 * WN;
  bf16_t* W2b = wb + 5 * WN;

  dim3 sgrid(16, 32);                          // 512 blocks (swizzled in-kernel)

  prep_kernel<<<B_ * S_ + 6 * (D_ * D_ / 1024), 256, 0, stream>>>(
      query, key, value, qpe, kpe, vpe, Wq, Wk, Wv, Wo, W1, W2, wb);

  gemm_qkv<<<dim3(8, 32, 3), 256, 0, stream>>>(
      qpe, kpe, vpe, Wqb, Wkb, Wvb, Qp, Kp, Vt);

  attn_kernel<<<dim3(S_ / 128, B_ * H_), 256, 0, stream>>>(Qp, Kp, Vt, ctx);

  gemm_s<0><<<sgrid, 256, 0, stream>>>(ctx, Wob, nullptr, ao);
  add_ln_kernel<bf16_t><<<B_ * S_, 256, 0, stream>>>(ao, qpe, g1, be1, x1);

  gemm_s<2><<<sgrid, 256, 0, stream>>>(x1, W1b, b1, hh);
  gemm_s<1><<<sgrid, 256, 0, stream>>>(hh, W2b, b2, ff);
  add_ln_kernel<float><<<B_ * S_, 256, 0, stream>>>(ff, x1, g2, be2, out);
}